// Round 7
// baseline (421.092 us; speedup 1.0000x reference)
//
#include <hip/hip_runtime.h>
#include <math.h>

#define TAU_F 0.6f

typedef short short8 __attribute__((ext_vector_type(8)));
typedef float floatx4 __attribute__((ext_vector_type(4)));
typedef int   intx4  __attribute__((ext_vector_type(4)));

__device__ __forceinline__ ushort f2bf(float f) {
    unsigned u = __float_as_uint(f);
    u += 0x7FFF + ((u >> 16) & 1);
    return (ushort)(u >> 16);
}
__device__ __forceinline__ float bf2f(ushort h) {
    return __uint_as_float(((unsigned)h) << 16);
}
__device__ __forceinline__ int swz(int row, int j, int mask) { return j ^ (row & mask); }

// packed fp32x2 -> bf16x2 (RNE), single VOP3 instruction
__device__ __forceinline__ unsigned cvt_pk_bf16(float lo, float hi) {
    unsigned r;
    asm("v_cvt_pk_bf16_f32 %0, %1, %2" : "=v"(r) : "v"(lo), "v"(hi));
    return r;
}
// raw v_exp_f32 (computes 2^x)
__device__ __forceinline__ float exp2_fast(float x) {
    float r; asm("v_exp_f32 %0, %1" : "=v"(r) : "v"(x)); return r;
}

// Stage a tile from global into LDS with XOR-chunk swizzle via global_load_lds (16B).
// SC = number of 1KB superchunks; CPR = 16B chunks per row; NW = waves in block.
template<int CPR, int SC, int NW = 4>
__device__ __forceinline__ void stage_swz(void* lds, const char* g, int rowstride_bytes,
                                          int w, int lane)
{
    #pragma unroll
    for (int p = 0; p < (SC + NW - 1) / NW; ++p) {
        int sc = w + p * NW;
        if (SC % NW != 0 && sc >= SC) break;
        int LC = sc * 64 + lane;
        int r = LC / CPR;
        int s = LC % CPR;
        int j = s ^ (r & (CPR - 1));
        const char* gp = g + (size_t)r * rowstride_bytes + j * 16;
        __builtin_amdgcn_global_load_lds(
            (const __attribute__((address_space(1))) void*)gp,
            (__attribute__((address_space(3))) void*)((char*)lds + sc * 1024), 16, 0, 0);
    }
}

// ===================== MFMA NT GEMM (bf16): C[M,N] = A[M,K] * Bt[N,K]^T + bias ==========
__global__ __launch_bounds__(256) void gemm_nt_kernel(
    const ushort* __restrict__ Ah, int lda,
    const ushort* __restrict__ Bh, int ldb,
    const float* __restrict__ bias, float* __restrict__ C, int ldc, int K)
{
    __shared__ __align__(16) ushort As_h[128 * 32];
    __shared__ __align__(16) ushort Bs_h[128 * 32];
    const int tid = threadIdx.x;
    const int w = tid >> 6, lane = tid & 63;
    const int quad = lane >> 4, c15 = lane & 15;
    const int wm = w >> 1, wn = w & 1;
    const int bm = blockIdx.y * 128, bn = blockIdx.x * 128;

    floatx4 acc[4][4];
    #pragma unroll
    for (int i = 0; i < 4; i++)
        #pragma unroll
        for (int j = 0; j < 4; j++) acc[i][j] = (floatx4){0.f, 0.f, 0.f, 0.f};

    const char* Ab = (const char*)(Ah + (size_t)bm * lda);
    const char* Bb = (const char*)(Bh + (size_t)bn * ldb);

    for (int k0 = 0; k0 < K; k0 += 32) {
        stage_swz<4, 8>(As_h, Ab + k0 * 2, lda * 2, w, lane);
        stage_swz<4, 8>(Bs_h, Bb + k0 * 2, ldb * 2, w, lane);
        __syncthreads();
        short8 a_h[4], b_h[4];
        #pragma unroll
        for (int mt = 0; mt < 4; mt++) {
            int row = wm * 64 + mt * 16 + c15;
            a_h[mt] = *(const short8*)&As_h[row * 32 + swz(row, quad, 3) * 8];
        }
        #pragma unroll
        for (int nt = 0; nt < 4; nt++) {
            int row = wn * 64 + nt * 16 + c15;
            b_h[nt] = *(const short8*)&Bs_h[row * 32 + swz(row, quad, 3) * 8];
        }
        #pragma unroll
        for (int mt = 0; mt < 4; mt++)
            #pragma unroll
            for (int nt = 0; nt < 4; nt++)
                acc[mt][nt] = __builtin_amdgcn_mfma_f32_16x16x32_bf16(a_h[mt], b_h[nt], acc[mt][nt], 0, 0, 0);
        __syncthreads();
    }
    #pragma unroll
    for (int mt = 0; mt < 4; mt++)
        #pragma unroll
        for (int nt = 0; nt < 4; nt++) {
            int col = bn + wn * 64 + nt * 16 + c15;
            float bs = bias ? bias[col] : 0.f;
            #pragma unroll
            for (int r = 0; r < 4; r++) {
                int row = bm + wm * 64 + mt * 16 + quad * 4 + r;
                C[(size_t)row * ldc + col] = acc[mt][nt][r] + bs;
            }
        }
}

// ===================== MFMA NT GEMM, 128x64 tile (for N-small GEMMs: more blocks) =========
__global__ __launch_bounds__(256) void gemm_nt64_kernel(
    const ushort* __restrict__ Ah, int lda,
    const ushort* __restrict__ Bh, int ldb,
    const float* __restrict__ bias, float* __restrict__ C, int ldc, int K)
{
    __shared__ __align__(16) ushort As_h[128 * 32];
    __shared__ __align__(16) ushort Bs_h[64 * 32];
    const int tid = threadIdx.x;
    const int w = tid >> 6, lane = tid & 63;
    const int quad = lane >> 4, c15 = lane & 15;
    const int wm = w >> 1, wn = w & 1;
    const int bm = blockIdx.y * 128, bn = blockIdx.x * 64;

    floatx4 acc[4][2];
    #pragma unroll
    for (int i = 0; i < 4; i++)
        #pragma unroll
        for (int j = 0; j < 2; j++) acc[i][j] = (floatx4){0.f, 0.f, 0.f, 0.f};

    const char* Ab = (const char*)(Ah + (size_t)bm * lda);
    const char* Bb = (const char*)(Bh + (size_t)bn * ldb);

    for (int k0 = 0; k0 < K; k0 += 32) {
        stage_swz<4, 8>(As_h, Ab + k0 * 2, lda * 2, w, lane);
        stage_swz<4, 4>(Bs_h, Bb + k0 * 2, ldb * 2, w, lane);
        __syncthreads();
        short8 a_h[4], b_h[2];
        #pragma unroll
        for (int mt = 0; mt < 4; mt++) {
            int row = wm * 64 + mt * 16 + c15;
            a_h[mt] = *(const short8*)&As_h[row * 32 + swz(row, quad, 3) * 8];
        }
        #pragma unroll
        for (int nt = 0; nt < 2; nt++) {
            int row = wn * 32 + nt * 16 + c15;
            b_h[nt] = *(const short8*)&Bs_h[row * 32 + swz(row, quad, 3) * 8];
        }
        #pragma unroll
        for (int mt = 0; mt < 4; mt++)
            #pragma unroll
            for (int nt = 0; nt < 2; nt++)
                acc[mt][nt] = __builtin_amdgcn_mfma_f32_16x16x32_bf16(a_h[mt], b_h[nt], acc[mt][nt], 0, 0, 0);
        __syncthreads();
    }
    #pragma unroll
    for (int mt = 0; mt < 4; mt++)
        #pragma unroll
        for (int nt = 0; nt < 2; nt++) {
            int col = bn + wn * 32 + nt * 16 + c15;
            float bs = bias ? bias[col] : 0.f;
            #pragma unroll
            for (int r = 0; r < 4; r++) {
                int row = bm + wm * 64 + mt * 16 + quad * 4 + r;
                C[(size_t)row * ldc + col] = acc[mt][nt][r] + bs;
            }
        }
}

// ===================== sim GEMM (int8, K=64 MFMA) with fused per-row max/argmax ==========
// A [4096][1024] i8, B [8192][1024] i8 (k0||k1), both rows pre-normalized+quantized x127.
__global__ __launch_bounds__(256) void simmax_i8(
    const char* __restrict__ A, const char* __restrict__ B,
    float* __restrict__ pval, int* __restrict__ pidx)
{
    __shared__ __align__(16) char As_b[128 * 64];
    __shared__ __align__(16) char Bs_b[128 * 64];
    __shared__ float redv[128][2];
    __shared__ int   redi[128][2];
    const int tid = threadIdx.x;
    const int w = tid >> 6, lane = tid & 63;
    const int quad = lane >> 4, c15 = lane & 15;
    const int wm = w >> 1, wn = w & 1;
    const int bm = blockIdx.y * 128, bn = blockIdx.x * 128;

    intx4 acc[4][4];
    #pragma unroll
    for (int i = 0; i < 4; i++)
        #pragma unroll
        for (int j = 0; j < 4; j++) acc[i][j] = (intx4){0, 0, 0, 0};

    const char* Ab = A + (size_t)bm * 1024;
    const char* Bb = B + (size_t)bn * 1024;

    for (int k0 = 0; k0 < 1024; k0 += 64) {
        stage_swz<4, 8>(As_b, Ab + k0, 1024, w, lane);
        stage_swz<4, 8>(Bs_b, Bb + k0, 1024, w, lane);
        __syncthreads();
        intx4 a_f[4], b_f[4];
        #pragma unroll
        for (int mt = 0; mt < 4; mt++) {
            int row = wm * 64 + mt * 16 + c15;
            a_f[mt] = *(const intx4*)&As_b[row * 64 + swz(row, quad, 3) * 16];
        }
        #pragma unroll
        for (int nt = 0; nt < 4; nt++) {
            int row = wn * 64 + nt * 16 + c15;
            b_f[nt] = *(const intx4*)&Bs_b[row * 64 + swz(row, quad, 3) * 16];
        }
        #pragma unroll
        for (int mt = 0; mt < 4; mt++)
            #pragma unroll
            for (int nt = 0; nt < 4; nt++)
                acc[mt][nt] = __builtin_amdgcn_mfma_i32_16x16x64_i8(a_f[mt], b_f[nt], acc[mt][nt], 0, 0, 0);
        __syncthreads();
    }
    const float isc = 1.0f / 16129.0f;   // 1/(127*127)
    #pragma unroll
    for (int mt = 0; mt < 4; mt++)
        #pragma unroll
        for (int r = 0; r < 4; r++) {
            float bv = -1e30f; int bi = 0;
            #pragma unroll
            for (int nt = 0; nt < 4; nt++) {
                float v = (float)acc[mt][nt][r] * isc;
                int col = bn + wn * 64 + nt * 16 + c15;
                if (v > bv) { bv = v; bi = col; }
            }
            #pragma unroll
            for (int m = 1; m < 16; m <<= 1) {
                float ov = __shfl_xor(bv, m, 64);
                int   oi = __shfl_xor(bi, m, 64);
                if (ov > bv || (ov == bv && oi < bi)) { bv = ov; bi = oi; }
            }
            if (c15 == 0) {
                int row = wm * 64 + mt * 16 + quad * 4 + r;
                redv[row][wn] = bv; redi[row][wn] = bi;
            }
        }
    __syncthreads();
    if (tid < 128) {
        float v0 = redv[tid][0], v1 = redv[tid][1];
        int   i0 = redi[tid][0], i1 = redi[tid][1];
        bool t = (v1 > v0) || (v1 == v0 && i1 < i0);
        pval[(size_t)blockIdx.x * 4096 + bm + tid] = t ? v1 : v0;
        pidx[(size_t)blockIdx.x * 4096 + bm + tid] = t ? i1 : i0;
    }
}

// fused reduce for both halves
__global__ void simreduce2_kernel(const float* __restrict__ pval, const int* __restrict__ pidx,
                                  float* __restrict__ bv0, int* __restrict__ bi0,
                                  float* __restrict__ bv1, int* __restrict__ bi1)
{
    const int n = blockIdx.x * 256 + threadIdx.x;
    float best = -1e30f; int besti = 0x7fffffff;
    for (int c = 0; c < 32; c++) {
        float v = pval[(size_t)c * 4096 + n]; int ix = pidx[(size_t)c * 4096 + n];
        if (v > best || (v == best && ix < besti)) { best = v; besti = ix; }
    }
    bv0[n] = best; bi0[n] = besti;
    best = -1e30f; besti = 0x7fffffff;
    for (int c = 32; c < 64; c++) {
        float v = pval[(size_t)c * 4096 + n]; int ix = pidx[(size_t)c * 4096 + n];
        if (v > best || (v == best && ix < besti)) { best = v; besti = ix; }
    }
    bv1[n] = best; bi1[n] = besti - 4096;
}

// ===================== conversions =====================
__global__ __launch_bounds__(256) void xconv_kernel(const float* __restrict__ s,
                                                    ushort* __restrict__ dh)
{
    const int i = blockIdx.x * 256 + threadIdx.x;
    float4 v = ((const float4*)s)[i];
    ushort4 h;
    h.x = f2bf(v.x); h.y = f2bf(v.y); h.z = f2bf(v.z); h.w = f2bf(v.w);
    ((ushort4*)dh)[i] = h;
}

__global__ __launch_bounds__(256) void wtrans_kernel(const float* __restrict__ src, int R, int Cc,
                                                     ushort* __restrict__ dh)
{
    __shared__ float t[64][65];
    const int tid = threadIdx.x;
    const int c0 = blockIdx.x * 64, r0 = blockIdx.y * 64;
    #pragma unroll
    for (int i = 0; i < 16; i++) {
        int lin = i * 256 + tid;
        int rr = lin >> 6, cc = lin & 63;
        t[rr][cc] = src[(size_t)(r0 + rr) * Cc + c0 + cc];
    }
    __syncthreads();
    #pragma unroll
    for (int i = 0; i < 16; i++) {
        int lin = i * 256 + tid;
        int cc2 = lin >> 6, rr2 = lin & 63;
        dh[(size_t)(c0 + cc2) * R + r0 + rr2] = f2bf(t[rr2][cc2]);
    }
}

__device__ __forceinline__ char q127(float v) {
    float c = fminf(fmaxf(v * 127.0f, -127.0f), 127.0f);
    return (char)__float2int_rn(c);
}

// y=0..2: l2-normalize rows -> int8 (sim path). y=3: q mh_rms -> bf16 [h][n][d].
// grid (4096, 4), 256 threads.
__global__ __launch_bounds__(256) void prep_kernel(const float* __restrict__ QKV,
                                                   const float* __restrict__ k0,
                                                   const float* __restrict__ k1,
                                                   const float* __restrict__ gamma_q,
                                                   char* __restrict__ kq,       // [4096][1024] i8
                                                   char* __restrict__ k01q,     // [8192][1024] i8
                                                   ushort* __restrict__ Qbh)    // [16][4096][64]
{
    const int n = blockIdx.x, t = threadIdx.x, y = blockIdx.y;
    if (y == 3) {
        // q: per-head rms (16 lanes per head), write bf16 [h][n][d]
        float4 v = ((const float4*)(QKV + (size_t)n * 3072))[t];
        float hs = v.x * v.x + v.y * v.y + v.z * v.z + v.w * v.w;
        #pragma unroll
        for (int m = 1; m < 16; m <<= 1) hs += __shfl_xor(hs, m, 64);
        float inv = 8.0f / fmaxf(sqrtf(hs), 1e-12f);
        float4 g = ((const float4*)gamma_q)[t];
        const int h = t >> 4;
        size_t o = ((size_t)h * 4096 + n) * 64 + 4 * (t & 15);
        ushort4 hh;
        hh.x = f2bf(v.x * inv * g.x);
        hh.y = f2bf(v.y * inv * g.y);
        hh.z = f2bf(v.z * inv * g.z);
        hh.w = f2bf(v.w * inv * g.w);
        *(ushort4*)(Qbh + o) = hh;
        return;
    }
    const float* src; int ld; char* dst;
    if (y == 0)      { src = QKV + 1024; ld = 3072; dst = kq; }
    else if (y == 1) { src = k0; ld = 1024; dst = k01q; }
    else             { src = k1; ld = 1024; dst = k01q + (size_t)4096 * 1024; }
    float4 v = *(const float4*)(src + (size_t)n * ld + 4 * t);
    float ss = v.x * v.x + v.y * v.y + v.z * v.z + v.w * v.w;
    #pragma unroll
    for (int off = 32; off; off >>= 1) ss += __shfl_xor(ss, off, 64);
    __shared__ float wsum[4];
    if ((t & 63) == 0) wsum[t >> 6] = ss;
    __syncthreads();
    float inv = 1.0f / fmaxf(sqrtf(wsum[0] + wsum[1] + wsum[2] + wsum[3]), 1e-12f);
    char4 o;
    o.x = q127(v.x * inv); o.y = q127(v.y * inv);
    o.z = q127(v.z * inv); o.w = q127(v.w * inv);
    *(char4*)(dst + (size_t)n * 1024 + 4 * t) = o;
}

// combine + per-head mh_rms(k) -> CKh [16][4096][64]; CV fp32 + per-block sumsq partials
__global__ __launch_bounds__(256) void combine_kernel(
    const float* __restrict__ QKV,
    const float* __restrict__ k0, const float* __restrict__ v0,
    const float* __restrict__ k1, const float* __restrict__ v1,
    const float* __restrict__ bv0, const int* __restrict__ bi0,
    const float* __restrict__ bv1, const int* __restrict__ bi1,
    const float* __restrict__ gamma_k,
    ushort* __restrict__ CKh,
    float* __restrict__ CV, float* __restrict__ pps)   // pps[2][4096]
{
    const int n = blockIdx.x, t = threadIdx.x;
    const bool va0 = bv0[n] > TAU_F; const int i0 = bi0[n];
    const bool va1 = bv1[n] > TAU_F; const int i1 = bi1[n];
    float4 kf = ((const float4*)(QKV + (size_t)n * 3072 + 1024))[t];
    float4 vf = ((const float4*)(QKV + (size_t)n * 3072 + 2048))[t];
    float4 kg0 = va0 ? ((const float4*)(k0 + (size_t)i0 * 1024))[t] : kf;
    float4 vg0 = va0 ? ((const float4*)(v0 + (size_t)i0 * 1024))[t] : vf;
    float4 kg1 = va1 ? ((const float4*)(k1 + (size_t)i1 * 1024))[t] : kf;
    float4 vg1 = va1 ? ((const float4*)(v1 + (size_t)i1 * 1024))[t] : vf;
    float4 ck, cv;
    ck.x = 0.5f * kg0.x + 0.5f * kg1.x + kf.x;
    ck.y = 0.5f * kg0.y + 0.5f * kg1.y + kf.y;
    ck.z = 0.5f * kg0.z + 0.5f * kg1.z + kf.z;
    ck.w = 0.5f * kg0.w + 0.5f * kg1.w + kf.w;
    cv.x = 0.5f * vg0.x + 0.5f * vg1.x + vf.x;
    cv.y = 0.5f * vg0.y + 0.5f * vg1.y + vf.y;
    cv.z = 0.5f * vg0.z + 0.5f * vg1.z + vf.z;
    cv.w = 0.5f * vg0.w + 0.5f * vg1.w + vf.w;
    ((float4*)(CV + (size_t)n * 1024))[t] = cv;
    float s0 = vf.x * vf.x + vf.y * vf.y + vf.z * vf.z + vf.w * vf.w;
    float s1 = cv.x * cv.x + cv.y * cv.y + cv.z * cv.z + cv.w * cv.w;
    #pragma unroll
    for (int off = 32; off; off >>= 1) {
        s0 += __shfl_xor(s0, off, 64);
        s1 += __shfl_xor(s1, off, 64);
    }
    __shared__ float w0[4], w1[4];
    if ((t & 63) == 0) { w0[t >> 6] = s0; w1[t >> 6] = s1; }
    float hs = ck.x * ck.x + ck.y * ck.y + ck.z * ck.z + ck.w * ck.w;
    #pragma unroll
    for (int m = 1; m < 16; m <<= 1) hs += __shfl_xor(hs, m, 64);
    float inv = 8.0f / fmaxf(sqrtf(hs), 1e-12f);
    float4 g = ((const float4*)gamma_k)[t];
    const int h = t >> 4;
    size_t o = ((size_t)h * 4096 + n) * 64 + 4 * (t & 15);
    ushort4 hh;
    hh.x = f2bf(ck.x * inv * g.x);
    hh.y = f2bf(ck.y * inv * g.y);
    hh.z = f2bf(ck.z * inv * g.z);
    hh.w = f2bf(ck.w * inv * g.w);
    *(ushort4*)(CKh + o) = hh;
    __syncthreads();
    // per-block partial sums (plain stores) -> reduced by sumred_kernel.
    // 4096x2 contended atomicAdds to one address cost ~110us of serialization here.
    if (t == 0) {
        pps[n]        = w0[0] + w0[1] + w0[2] + w0[3];
        pps[4096 + n] = w1[0] + w1[1] + w1[2] + w1[3];
    }
}

// reduce pps[2][4096] -> ss[2]  (one block)
__global__ __launch_bounds__(256) void sumred_kernel(const float* __restrict__ pps,
                                                     float* __restrict__ ss)
{
    const int t = threadIdx.x;
    float a = 0.f, b = 0.f;
    #pragma unroll 4
    for (int i = t; i < 4096; i += 256) { a += pps[i]; b += pps[4096 + i]; }
    #pragma unroll
    for (int off = 32; off; off >>= 1) {
        a += __shfl_xor(a, off, 64);
        b += __shfl_xor(b, off, 64);
    }
    __shared__ float sa[4], sb[4];
    if ((t & 63) == 0) { sa[t >> 6] = a; sb[t >> 6] = b; }
    __syncthreads();
    if (t == 0) {
        ss[0] = sa[0] + sa[1] + sa[2] + sa[3];
        ss[1] = sb[0] + sb[1] + sb[2] + sb[3];
    }
}

// CV fp32 [4096][1024] --(*sv)--> Vt bf16 [1024][4096]
__global__ __launch_bounds__(256) void vt_kernel(const float* __restrict__ CV,
                                                 const float* __restrict__ ss,
                                                 ushort* __restrict__ Vt)
{
    __shared__ float t[64][65];
    const float sv = sqrtf(ss[0] / ss[1]);
    const int tid = threadIdx.x;
    const int n0 = blockIdx.x * 64, d0 = blockIdx.y * 64;
    #pragma unroll
    for (int i = 0; i < 16; i++) {
        int lin = i * 256 + tid;
        int r = lin >> 6, c = lin & 63;
        t[r][c] = CV[(size_t)(n0 + r) * 1024 + d0 + c];
    }
    __syncthreads();
    #pragma unroll
    for (int i = 0; i < 16; i++) {
        int lin = i * 256 + tid;
        int dr = lin >> 6, nc = lin & 63;
        Vt[(size_t)(d0 + dr) * 4096 + n0 + nc] = f2bf(t[nc][dr] * sv);
    }
}

// ===================== flash attention v5: 4 waves x 32 q-rows, KVBLK=64 ==========
// grid (32 q-tiles, 16 heads), 256 threads = 4 waves, 32 q-rows each (2 groups of 16).
// LDS-pipe-bound fix: each wave's 8 K-reads + 8 V-reads per iter now feed 32 MFMAs
// (2 q-groups share ka/kb/vb) instead of 16 -> ~1.8x fewer LDS bytes per FLOP.
// LDS = 2x8K (K) + 2x8K (V) + 16K (Ps 128 rows) = 48 KB.
// Fixed-max softmax (|q|=|k|=8 per head): p=exp(s/8-8.5) <= 1, no online-max state.
// Swapped QK^T (mfma(K,Q) -> S^T): lane holds 4 consecutive keys for one q row;
// P -> bf16 via v_cvt_pk_bf16_f32 + one ds_write_b64 per 4 elements.
__global__ __launch_bounds__(256, 2) void attn_mfma(
    const ushort* __restrict__ Qh,   // [16][4096][64]
    const ushort* __restrict__ Kh,   // [16][4096][64]
    const ushort* __restrict__ Vt,   // [16*64][4096]
    ushort* __restrict__ Hb)         // [4096][1024]
{
    __shared__ __align__(16) ushort Ks[2][64 * 64];    // 2 x 8 KB  [kv][d]
    __shared__ __align__(16) ushort Vs[2][64 * 64];    // 2 x 8 KB  [d][kv]
    __shared__ __align__(16) ushort Ps[128 * 64];      // 16 KB, wave-private rows
    const int h = blockIdx.y;
    const int n0 = blockIdx.x * 128;
    const int tid = threadIdx.x;
    const int w = tid >> 6, lane = tid & 63;
    const int quad = lane >> 4, c15 = lane & 15;

    // two q-row groups per wave: rows w*32 + g*16 + c15
    short8 qf[2][2];
    #pragma unroll
    for (int g = 0; g < 2; g++)
        #pragma unroll
        for (int kh = 0; kh < 2; kh++)
            qf[g][kh] = *(const short8*)(Qh + ((size_t)h * 4096 + n0 + w * 32 + g * 16 + c15) * 64
                                         + kh * 32 + quad * 8);

    floatx4 po[2][4];
    #pragma unroll
    for (int g = 0; g < 2; g++)
        #pragma unroll
        for (int nt = 0; nt < 4; nt++) po[g][nt] = (floatx4){0.f, 0.f, 0.f, 0.f};
    float lsum[2] = {0.f, 0.f};

    // p = exp(s*0.125 - 8.5) = exp2(s*(log2e/8) - 8.5*log2e)
    const float KSC = 0.18033688011112042f;     // log2(e)/8
    const float KBI = -12.262907847556189f;     // -8.5*log2(e)

    const int pr0 = w * 32 + c15;               // group-0 Ps row; group 1 = pr0 + 16
    const ushort* Kbase = Kh + (size_t)h * 4096 * 64;
    const ushort* Vbase = Vt + (size_t)h * 64 * 4096;

    // prologue: stage tile 0 into buffer 0 (64 kv rows x 64 d; rows are 128B = 8 chunks)
    stage_swz<8, 8, 4>(Ks[0], (const char*)(Kbase + 0), 128, w, lane);
    stage_swz<8, 8, 4>(Vs[0], (const char*)(Vbase + 0), 8192, w, lane);
    __syncthreads();

    int cur = 0;
    for (int it = 0; it < 64; ++it) {
        // issue next tile's loads into the other buffer (overlaps with compute below)
        if (it + 1 < 64) {
            const int m1 = (it + 1) * 64;
            stage_swz<8, 8, 4>(Ks[cur ^ 1], (const char*)(Kbase + (size_t)m1 * 64), 128, w, lane);
            stage_swz<8, 8, 4>(Vs[cur ^ 1], (const char*)(Vbase + m1), 8192, w, lane);
        }
        const ushort* Kc = Ks[cur];
        const ushort* Vc = Vs[cur];

        // QK^T: one ka/kb read pair serves BOTH q-groups (key LDS amortization)
        floatx4 s[2][4];
        #pragma unroll
        for (int nt = 0; nt < 4; nt++) {
            int rk = nt * 16 + c15;
            short8 ka = *(const short8*)&Kc[rk * 64 + swz(rk, quad, 7) * 8];
            short8 kb = *(const short8*)&Kc[rk * 64 + swz(rk, 4 + quad, 7) * 8];
            floatx4 z0 = (floatx4){0.f, 0.f, 0.f, 0.f};
            floatx4 z1 = (floatx4){0.f, 0.f, 0.f, 0.f};
            z0 = __builtin_amdgcn_mfma_f32_16x16x32_bf16(ka, qf[0][0], z0, 0, 0, 0);
            z0 = __builtin_amdgcn_mfma_f32_16x16x32_bf16(kb, qf[0][1], z0, 0, 0, 0);
            z1 = __builtin_amdgcn_mfma_f32_16x16x32_bf16(ka, qf[1][0], z1, 0, 0, 0);
            z1 = __builtin_amdgcn_mfma_f32_16x16x32_bf16(kb, qf[1][1], z1, 0, 0, 0);
            s[0][nt] = z0;
            s[1][nt] = z1;
        }
        // softmax partial: 4 consecutive keys per lane -> cvt_pk + single b64 write.
        // write swizzle (8B units): ch = (nt*4+quad) ^ ((row&7)<<1); its 16B view is
        // j ^ (row&7), identical to the read swizzle below.
        #pragma unroll
        for (int g = 0; g < 2; g++) {
            const int prg = pr0 + g * 16;
            #pragma unroll
            for (int nt = 0; nt < 4; nt++) {
                float p0 = exp2_fast(fmaf(s[g][nt][0], KSC, KBI));
                float p1 = exp2_fast(fmaf(s[g][nt][1], KSC, KBI));
                float p2 = exp2_fast(fmaf(s[g][nt][2], KSC, KBI));
                float p3 = exp2_fast(fmaf(s[g][nt][3], KSC, KBI));
                lsum[g] += (p0 + p1) + (p2 + p3);
                uint2 pk;
                pk.x = cvt_pk_bf16(p0, p1);
                pk.y = cvt_pk_bf16(p2, p3);
                int ch = (nt * 4 + quad) ^ ((prg & 7) << 1);
                *(uint2*)&Ps[prg * 64 + ch * 4] = pk;
            }
        }
        __builtin_amdgcn_wave_barrier();   // order Ps writes before cross-lane reads
        // PV: one vb read serves BOTH q-groups
        #pragma unroll
        for (int kb2 = 0; kb2 < 2; kb2++) {
            short8 pa0 = *(const short8*)&Ps[pr0 * 64 + swz(pr0, kb2 * 4 + quad, 7) * 8];
            short8 pa1 = *(const short8*)&Ps[(pr0 + 16) * 64 + swz(pr0 + 16, kb2 * 4 + quad, 7) * 8];
            #pragma unroll
            for (int nt = 0; nt < 4; nt++) {
                int dr = nt * 16 + c15;
                int j = kb2 * 4 + quad;
                short8 vb = *(const short8*)&Vc[dr * 64 + swz(dr, j, 7) * 8];
                po[0][nt] = __builtin_amdgcn_mfma_f32_16x16x32_bf16(pa0, vb, po[0][nt], 0, 0, 0);
                po[1][nt] = __builtin_amdgcn_mfma_f32_16x16x32_bf16(pa1, vb, po[1][nt], 0, 0, 0);
            }
        }
        // one barrier per iter: drains this wave's staged loads (vmcnt) + LDS ops,
        // so after it the OTHER buffer is fully populated for the next iteration.
        __syncthreads();
        cur ^= 1;
    }
    // lsum[g] is per (q=c15, quad-partial); reduce across quads -> full l per q=c15
    #pragma unroll
    for (int g = 0; g < 2; g++) {
        float l = lsum[g];
        l += __shfl_xor(l, 16, 64);
        l += __shfl_xor(l, 32, 64);
        #pragma unroll
        for (int r = 0; r < 4; r++) {
            float lr = __shfl(l, quad * 4 + r, 64);   // l for output q-row quad*4+r
            float inv = 1.0f / lr;
            int row = n0 + w * 32 + g * 16 + quad * 4 + r;
            #pragma unroll
            for (int nt = 0; nt < 4; nt++)
                Hb[(size_t)row * 1024 + h * 64 + nt * 16 + c15] = f2bf(po[g][nt][r] * inv);
        }
    }
}

// ===================== launcher =====================
extern "C" void kernel_launch(void* const* d_in, const int* in_sizes, int n_in,
                              void* d_out, int out_size, void* d_ws, size_t ws_size,
                              hipStream_t stream)
{
    const float* x       = (const float*)d_in[0];
    const float* k0      = (const float*)d_in[1];
    const float* v0      = (const float*)d_in[2];
    const float* k1      = (const float*)d_in[3];
    const float* v1      = (const float*)d_in[4];
    const float* W_qkv   = (const float*)d_in[5];
    const float* b_qkv   = (const float*)d_in[6];
    const float* gamma_q = (const float*)d_in[7];
    const float* gamma_k = (const float*)d_in[8];
    const float* W_out   = (const float*)d_in[9];
    const float* b_out   = (const float*)d_in[10];
    float* out = (float*)d_out;

    char* W = (char*)d_ws;
    // Region A (0..48M): QKV fp32; after combine reused for Vt + Hb
    float*  QKV = (float*)(W + 0);
    ushort* Vt  = (ushort*)(W + 0);
    ushort* Hb  = (ushort*)(W + 8388608);
    // Region B (48M..56M): Qb
    ushort* Qbh = (ushort*)(W + 50331648);
    // Region C (64M..96M): phased
    ushort* xh   = (ushort*)(W + 67108864);                 // 8 MB   (phase 1)
    ushort* Wqh  = (ushort*)(W + 67108864 + 8388608);       // 6 MB   (phase 1)
    char*   kq   = (char*)(W + 67108864);                   // 4 MB   (phase 2)
    char*   k01q = (char*)(W + 67108864 + 4194304);         // 8 MB   (phase 2)
    float*  pval = (float*)(W + 67108864 + 25165824);       // 1 MB
    int*    pidx = (int*)  (W + 67108864 + 26214400);       // 1 MB
    float*  CV   = (float*)(W + 67108864);                  // 16 MB  (phase 3)
    ushort* CKh  = (ushort*)(W + 67108864 + 16777216);      // 8 MB   (phase 3)
    ushort* Wob  = (ushort*)(W + 67108864);                 // 2 MB   (phase 4, CV dead)
    // Region D (96M..): small
    float* bv0  = (float*)(W + 100663296);
    int*   bi0  = (int*)  (W + 100663296 + 16384);
    float* bv1  = (float*)(W + 100663296 + 32768);
    int*   bi1  = (int*)  (W + 100663296 + 49152);
    float* ssum = (float*)(W + 100663296 + 65536);
    float* pps  = (float*)(W + 100663296 + 131072);         // 32 KB [2][4096]

    // 1. convert inputs for QKV GEMM (plain bf16)
    xconv_kernel<<<4096, 256, 0, stream>>>(x, xh);
    wtrans_kernel<<<dim3(48, 16), 256, 0, stream>>>(W_qkv, 1024, 3072, Wqh);
    // 2. QKV = x @ W_qkv + b (plain bf16)
    gemm_nt_kernel<<<dim3(24, 32), 256, 0, stream>>>(xh, 1024, Wqh, 1024,
                                                     b_qkv, QKV, 3072, 1024);
    // 3. prep: q mh_rms->bf16 [h][n][d] + i8-normalized rows for sim (one launch)
    prep_kernel<<<dim3(4096, 4), 256, 0, stream>>>(QKV, k0, k1, gamma_q, kq, k01q, Qbh);
    // 4. sim + top-1 over concatenated [k0;k1] (int8 MFMA, 2x rate)
    simmax_i8<<<dim3(64, 32), 256, 0, stream>>>(kq, k01q, pval, pidx);
    simreduce2_kernel<<<16, 256, 0, stream>>>(pval, pidx, bv0, bi0, bv1, bi1);
    // 5. combine (+mh_rms k fused; sk cancels) -> CKh, CV fp32, sumsq partials
    combine_kernel<<<4096, 256, 0, stream>>>(QKV, k0, v0, k1, v1, bv0, bi0, bv1, bi1,
                                             gamma_k, CKh, CV, pps);
    // 5b. reduce partials -> ssum (replaces 8192 same-address atomics, ~110us saved)
    sumred_kernel<<<1, 256, 0, stream>>>(pps, ssum);
    // 6. V: scale by sv + transpose -> Vt bf16 [1024][4096]
    vt_kernel<<<dim3(64, 16), 256, 0, stream>>>(CV, ssum, Vt);
    // 7. W_out transpose -> bf16 (CV dead now)
    wtrans_kernel<<<dim3(16, 16), 256, 0, stream>>>(W_out, 1024, 1024, Wob);
    // 8. flash attention v5 (4 waves x 32 q-rows: K/V LDS reads amortized over 2x MFMA)
    attn_mfma<<<dim3(32, 16), 256, 0, stream>>>(Qbh, CKh, Vt, Hb);
    // 9. out = Hb @ W_out^T + b_out (128x64 tiles -> 512 blocks for occupancy)
    gemm_nt64_kernel<<<dim3(16, 32), 256, 0, stream>>>(Hb, 1024, Wob, 1024,
                                                       b_out, out, 1024, 1024);
}

// Round 8
// 414.447 us; speedup vs baseline: 1.0160x; 1.0160x over previous
//
#include <hip/hip_runtime.h>
#include <math.h>

#define TAU_F 0.6f

typedef short short8 __attribute__((ext_vector_type(8)));
typedef float floatx4 __attribute__((ext_vector_type(4)));
typedef int   intx4  __attribute__((ext_vector_type(4)));

__device__ __forceinline__ ushort f2bf(float f) {
    unsigned u = __float_as_uint(f);
    u += 0x7FFF + ((u >> 16) & 1);
    return (ushort)(u >> 16);
}
__device__ __forceinline__ float bf2f(ushort h) {
    return __uint_as_float(((unsigned)h) << 16);
}
__device__ __forceinline__ int swz(int row, int j, int mask) { return j ^ (row & mask); }

// packed fp32x2 -> bf16x2 (RNE), single VOP3 instruction
__device__ __forceinline__ unsigned cvt_pk_bf16(float lo, float hi) {
    unsigned r;
    asm("v_cvt_pk_bf16_f32 %0, %1, %2" : "=v"(r) : "v"(lo), "v"(hi));
    return r;
}
// raw v_exp_f32 (computes 2^x)
__device__ __forceinline__ float exp2_fast(float x) {
    float r; asm("v_exp_f32 %0, %1" : "=v"(r) : "v"(x)); return r;
}

// XCD-aware bijective block remap (T1): hardware assigns linear id round-robin
// to the 8 XCDs; remap so each XCD owns a CONTIGUOUS range of logical tiles
// (L2 panel locality). Requires nwg % 8 == 0 (all our grids satisfy this).
__device__ __forceinline__ int xcd_remap(int id, int nwg) {
    return (id & 7) * (nwg >> 3) + (id >> 3);
}

// Stage a tile from global into LDS with XOR-chunk swizzle via global_load_lds (16B).
// SC = number of 1KB superchunks; CPR = 16B chunks per row; NW = waves in block.
template<int CPR, int SC, int NW = 4>
__device__ __forceinline__ void stage_swz(void* lds, const char* g, int rowstride_bytes,
                                          int w, int lane)
{
    #pragma unroll
    for (int p = 0; p < (SC + NW - 1) / NW; ++p) {
        int sc = w + p * NW;
        if (SC % NW != 0 && sc >= SC) break;
        int LC = sc * 64 + lane;
        int r = LC / CPR;
        int s = LC % CPR;
        int j = s ^ (r & (CPR - 1));
        const char* gp = g + (size_t)r * rowstride_bytes + j * 16;
        __builtin_amdgcn_global_load_lds(
            (const __attribute__((address_space(1))) void*)gp,
            (__attribute__((address_space(3))) void*)((char*)lds + sc * 1024), 16, 0, 0);
    }
}

// ===================== MFMA NT GEMM (bf16): C[M,N] = A[M,K] * Bt[N,K]^T + bias ==========
__global__ __launch_bounds__(256) void gemm_nt_kernel(
    const ushort* __restrict__ Ah, int lda,
    const ushort* __restrict__ Bh, int ldb,
    const float* __restrict__ bias, float* __restrict__ C, int ldc, int K)
{
    __shared__ __align__(16) ushort As_h[128 * 32];
    __shared__ __align__(16) ushort Bs_h[128 * 32];
    const int tid = threadIdx.x;
    const int w = tid >> 6, lane = tid & 63;
    const int quad = lane >> 4, c15 = lane & 15;
    const int wm = w >> 1, wn = w & 1;
    const int idl = blockIdx.y * gridDim.x + blockIdx.x;
    const int nid = xcd_remap(idl, gridDim.x * gridDim.y);
    const int bm = (nid / gridDim.x) * 128, bn = (nid % gridDim.x) * 128;

    floatx4 acc[4][4];
    #pragma unroll
    for (int i = 0; i < 4; i++)
        #pragma unroll
        for (int j = 0; j < 4; j++) acc[i][j] = (floatx4){0.f, 0.f, 0.f, 0.f};

    const char* Ab = (const char*)(Ah + (size_t)bm * lda);
    const char* Bb = (const char*)(Bh + (size_t)bn * ldb);

    for (int k0 = 0; k0 < K; k0 += 32) {
        stage_swz<4, 8>(As_h, Ab + k0 * 2, lda * 2, w, lane);
        stage_swz<4, 8>(Bs_h, Bb + k0 * 2, ldb * 2, w, lane);
        __syncthreads();
        short8 a_h[4], b_h[4];
        #pragma unroll
        for (int mt = 0; mt < 4; mt++) {
            int row = wm * 64 + mt * 16 + c15;
            a_h[mt] = *(const short8*)&As_h[row * 32 + swz(row, quad, 3) * 8];
        }
        #pragma unroll
        for (int nt = 0; nt < 4; nt++) {
            int row = wn * 64 + nt * 16 + c15;
            b_h[nt] = *(const short8*)&Bs_h[row * 32 + swz(row, quad, 3) * 8];
        }
        #pragma unroll
        for (int mt = 0; mt < 4; mt++)
            #pragma unroll
            for (int nt = 0; nt < 4; nt++)
                acc[mt][nt] = __builtin_amdgcn_mfma_f32_16x16x32_bf16(a_h[mt], b_h[nt], acc[mt][nt], 0, 0, 0);
        __syncthreads();
    }
    #pragma unroll
    for (int mt = 0; mt < 4; mt++)
        #pragma unroll
        for (int nt = 0; nt < 4; nt++) {
            int col = bn + wn * 64 + nt * 16 + c15;
            float bs = bias ? bias[col] : 0.f;
            #pragma unroll
            for (int r = 0; r < 4; r++) {
                int row = bm + wm * 64 + mt * 16 + quad * 4 + r;
                C[(size_t)row * ldc + col] = acc[mt][nt][r] + bs;
            }
        }
}

// ===================== MFMA NT GEMM, 128x64 tile (for N-small GEMMs: more blocks) =========
__global__ __launch_bounds__(256) void gemm_nt64_kernel(
    const ushort* __restrict__ Ah, int lda,
    const ushort* __restrict__ Bh, int ldb,
    const float* __restrict__ bias, float* __restrict__ C, int ldc, int K)
{
    __shared__ __align__(16) ushort As_h[128 * 32];
    __shared__ __align__(16) ushort Bs_h[64 * 32];
    const int tid = threadIdx.x;
    const int w = tid >> 6, lane = tid & 63;
    const int quad = lane >> 4, c15 = lane & 15;
    const int wm = w >> 1, wn = w & 1;
    const int idl = blockIdx.y * gridDim.x + blockIdx.x;
    const int nid = xcd_remap(idl, gridDim.x * gridDim.y);
    const int bm = (nid / gridDim.x) * 128, bn = (nid % gridDim.x) * 64;

    floatx4 acc[4][2];
    #pragma unroll
    for (int i = 0; i < 4; i++)
        #pragma unroll
        for (int j = 0; j < 2; j++) acc[i][j] = (floatx4){0.f, 0.f, 0.f, 0.f};

    const char* Ab = (const char*)(Ah + (size_t)bm * lda);
    const char* Bb = (const char*)(Bh + (size_t)bn * ldb);

    for (int k0 = 0; k0 < K; k0 += 32) {
        stage_swz<4, 8>(As_h, Ab + k0 * 2, lda * 2, w, lane);
        stage_swz<4, 4>(Bs_h, Bb + k0 * 2, ldb * 2, w, lane);
        __syncthreads();
        short8 a_h[4], b_h[2];
        #pragma unroll
        for (int mt = 0; mt < 4; mt++) {
            int row = wm * 64 + mt * 16 + c15;
            a_h[mt] = *(const short8*)&As_h[row * 32 + swz(row, quad, 3) * 8];
        }
        #pragma unroll
        for (int nt = 0; nt < 2; nt++) {
            int row = wn * 32 + nt * 16 + c15;
            b_h[nt] = *(const short8*)&Bs_h[row * 32 + swz(row, quad, 3) * 8];
        }
        #pragma unroll
        for (int mt = 0; mt < 4; mt++)
            #pragma unroll
            for (int nt = 0; nt < 2; nt++)
                acc[mt][nt] = __builtin_amdgcn_mfma_f32_16x16x32_bf16(a_h[mt], b_h[nt], acc[mt][nt], 0, 0, 0);
        __syncthreads();
    }
    #pragma unroll
    for (int mt = 0; mt < 4; mt++)
        #pragma unroll
        for (int nt = 0; nt < 2; nt++) {
            int col = bn + wn * 32 + nt * 16 + c15;
            float bs = bias ? bias[col] : 0.f;
            #pragma unroll
            for (int r = 0; r < 4; r++) {
                int row = bm + wm * 64 + mt * 16 + quad * 4 + r;
                C[(size_t)row * ldc + col] = acc[mt][nt][r] + bs;
            }
        }
}

// ===================== sim GEMM (int8, K=64 MFMA) with fused per-row max/argmax ==========
// A [4096][1024] i8, B [8192][1024] i8 (k0||k1), both rows pre-normalized+quantized x127.
__global__ __launch_bounds__(256) void simmax_i8(
    const char* __restrict__ A, const char* __restrict__ B,
    float* __restrict__ pval, int* __restrict__ pidx)
{
    __shared__ __align__(16) char As_b[128 * 64];
    __shared__ __align__(16) char Bs_b[128 * 64];
    __shared__ float redv[128][2];
    __shared__ int   redi[128][2];
    const int tid = threadIdx.x;
    const int w = tid >> 6, lane = tid & 63;
    const int quad = lane >> 4, c15 = lane & 15;
    const int wm = w >> 1, wn = w & 1;
    const int idl = blockIdx.y * gridDim.x + blockIdx.x;
    const int nid = xcd_remap(idl, gridDim.x * gridDim.y);
    const int bxn = nid % gridDim.x, byn = nid / gridDim.x;
    const int bm = byn * 128, bn = bxn * 128;

    intx4 acc[4][4];
    #pragma unroll
    for (int i = 0; i < 4; i++)
        #pragma unroll
        for (int j = 0; j < 4; j++) acc[i][j] = (intx4){0, 0, 0, 0};

    const char* Ab = A + (size_t)bm * 1024;
    const char* Bb = B + (size_t)bn * 1024;

    for (int k0 = 0; k0 < 1024; k0 += 64) {
        stage_swz<4, 8>(As_b, Ab + k0, 1024, w, lane);
        stage_swz<4, 8>(Bs_b, Bb + k0, 1024, w, lane);
        __syncthreads();
        intx4 a_f[4], b_f[4];
        #pragma unroll
        for (int mt = 0; mt < 4; mt++) {
            int row = wm * 64 + mt * 16 + c15;
            a_f[mt] = *(const intx4*)&As_b[row * 64 + swz(row, quad, 3) * 16];
        }
        #pragma unroll
        for (int nt = 0; nt < 4; nt++) {
            int row = wn * 64 + nt * 16 + c15;
            b_f[nt] = *(const intx4*)&Bs_b[row * 64 + swz(row, quad, 3) * 16];
        }
        #pragma unroll
        for (int mt = 0; mt < 4; mt++)
            #pragma unroll
            for (int nt = 0; nt < 4; nt++)
                acc[mt][nt] = __builtin_amdgcn_mfma_i32_16x16x64_i8(a_f[mt], b_f[nt], acc[mt][nt], 0, 0, 0);
        __syncthreads();
    }
    const float isc = 1.0f / 16129.0f;   // 1/(127*127)
    #pragma unroll
    for (int mt = 0; mt < 4; mt++)
        #pragma unroll
        for (int r = 0; r < 4; r++) {
            float bv = -1e30f; int bi = 0;
            #pragma unroll
            for (int nt = 0; nt < 4; nt++) {
                float v = (float)acc[mt][nt][r] * isc;
                int col = bn + wn * 64 + nt * 16 + c15;
                if (v > bv) { bv = v; bi = col; }
            }
            #pragma unroll
            for (int m = 1; m < 16; m <<= 1) {
                float ov = __shfl_xor(bv, m, 64);
                int   oi = __shfl_xor(bi, m, 64);
                if (ov > bv || (ov == bv && oi < bi)) { bv = ov; bi = oi; }
            }
            if (c15 == 0) {
                int row = wm * 64 + mt * 16 + quad * 4 + r;
                redv[row][wn] = bv; redi[row][wn] = bi;
            }
        }
    __syncthreads();
    if (tid < 128) {
        float v0 = redv[tid][0], v1 = redv[tid][1];
        int   i0 = redi[tid][0], i1 = redi[tid][1];
        bool t = (v1 > v0) || (v1 == v0 && i1 < i0);
        pval[(size_t)bxn * 4096 + bm + tid] = t ? v1 : v0;
        pidx[(size_t)bxn * 4096 + bm + tid] = t ? i1 : i0;
    }
}

// fused reduce for both halves
__global__ void simreduce2_kernel(const float* __restrict__ pval, const int* __restrict__ pidx,
                                  float* __restrict__ bv0, int* __restrict__ bi0,
                                  float* __restrict__ bv1, int* __restrict__ bi1)
{
    const int n = blockIdx.x * 256 + threadIdx.x;
    float best = -1e30f; int besti = 0x7fffffff;
    for (int c = 0; c < 32; c++) {
        float v = pval[(size_t)c * 4096 + n]; int ix = pidx[(size_t)c * 4096 + n];
        if (v > best || (v == best && ix < besti)) { best = v; besti = ix; }
    }
    bv0[n] = best; bi0[n] = besti;
    best = -1e30f; besti = 0x7fffffff;
    for (int c = 32; c < 64; c++) {
        float v = pval[(size_t)c * 4096 + n]; int ix = pidx[(size_t)c * 4096 + n];
        if (v > best || (v == best && ix < besti)) { best = v; besti = ix; }
    }
    bv1[n] = best; bi1[n] = besti - 4096;
}

// ===================== conversions =====================
__global__ __launch_bounds__(256) void xconv_kernel(const float* __restrict__ s,
                                                    ushort* __restrict__ dh)
{
    const int i = blockIdx.x * 256 + threadIdx.x;
    float4 v = ((const float4*)s)[i];
    ushort4 h;
    h.x = f2bf(v.x); h.y = f2bf(v.y); h.z = f2bf(v.z); h.w = f2bf(v.w);
    ((ushort4*)dh)[i] = h;
}

__global__ __launch_bounds__(256) void wtrans_kernel(const float* __restrict__ src, int R, int Cc,
                                                     ushort* __restrict__ dh)
{
    __shared__ float t[64][65];
    const int tid = threadIdx.x;
    const int c0 = blockIdx.x * 64, r0 = blockIdx.y * 64;
    #pragma unroll
    for (int i = 0; i < 16; i++) {
        int lin = i * 256 + tid;
        int rr = lin >> 6, cc = lin & 63;
        t[rr][cc] = src[(size_t)(r0 + rr) * Cc + c0 + cc];
    }
    __syncthreads();
    #pragma unroll
    for (int i = 0; i < 16; i++) {
        int lin = i * 256 + tid;
        int cc2 = lin >> 6, rr2 = lin & 63;
        dh[(size_t)(c0 + cc2) * R + r0 + rr2] = f2bf(t[rr2][cc2]);
    }
}

__device__ __forceinline__ char q127(float v) {
    float c = fminf(fmaxf(v * 127.0f, -127.0f), 127.0f);
    return (char)__float2int_rn(c);
}

// y=0..2: l2-normalize rows -> int8 (sim path). y=3: q mh_rms -> bf16 [h][n][d].
// grid (4096, 4), 256 threads.
__global__ __launch_bounds__(256) void prep_kernel(const float* __restrict__ QKV,
                                                   const float* __restrict__ k0,
                                                   const float* __restrict__ k1,
                                                   const float* __restrict__ gamma_q,
                                                   char* __restrict__ kq,       // [4096][1024] i8
                                                   char* __restrict__ k01q,     // [8192][1024] i8
                                                   ushort* __restrict__ Qbh)    // [16][4096][64]
{
    const int n = blockIdx.x, t = threadIdx.x, y = blockIdx.y;
    if (y == 3) {
        // q: per-head rms (16 lanes per head), write bf16 [h][n][d]
        float4 v = ((const float4*)(QKV + (size_t)n * 3072))[t];
        float hs = v.x * v.x + v.y * v.y + v.z * v.z + v.w * v.w;
        #pragma unroll
        for (int m = 1; m < 16; m <<= 1) hs += __shfl_xor(hs, m, 64);
        float inv = 8.0f / fmaxf(sqrtf(hs), 1e-12f);
        float4 g = ((const float4*)gamma_q)[t];
        const int h = t >> 4;
        size_t o = ((size_t)h * 4096 + n) * 64 + 4 * (t & 15);
        ushort4 hh;
        hh.x = f2bf(v.x * inv * g.x);
        hh.y = f2bf(v.y * inv * g.y);
        hh.z = f2bf(v.z * inv * g.z);
        hh.w = f2bf(v.w * inv * g.w);
        *(ushort4*)(Qbh + o) = hh;
        return;
    }
    const float* src; int ld; char* dst;
    if (y == 0)      { src = QKV + 1024; ld = 3072; dst = kq; }
    else if (y == 1) { src = k0; ld = 1024; dst = k01q; }
    else             { src = k1; ld = 1024; dst = k01q + (size_t)4096 * 1024; }
    float4 v = *(const float4*)(src + (size_t)n * ld + 4 * t);
    float ss = v.x * v.x + v.y * v.y + v.z * v.z + v.w * v.w;
    #pragma unroll
    for (int off = 32; off; off >>= 1) ss += __shfl_xor(ss, off, 64);
    __shared__ float wsum[4];
    if ((t & 63) == 0) wsum[t >> 6] = ss;
    __syncthreads();
    float inv = 1.0f / fmaxf(sqrtf(wsum[0] + wsum[1] + wsum[2] + wsum[3]), 1e-12f);
    char4 o;
    o.x = q127(v.x * inv); o.y = q127(v.y * inv);
    o.z = q127(v.z * inv); o.w = q127(v.w * inv);
    *(char4*)(dst + (size_t)n * 1024 + 4 * t) = o;
}

// combine + per-head mh_rms(k) -> CKh [16][4096][64]; CV fp32 + per-block sumsq partials
__global__ __launch_bounds__(256) void combine_kernel(
    const float* __restrict__ QKV,
    const float* __restrict__ k0, const float* __restrict__ v0,
    const float* __restrict__ k1, const float* __restrict__ v1,
    const float* __restrict__ bv0, const int* __restrict__ bi0,
    const float* __restrict__ bv1, const int* __restrict__ bi1,
    const float* __restrict__ gamma_k,
    ushort* __restrict__ CKh,
    float* __restrict__ CV, float* __restrict__ pps)   // pps[2][4096]
{
    const int n = blockIdx.x, t = threadIdx.x;
    const bool va0 = bv0[n] > TAU_F; const int i0 = bi0[n];
    const bool va1 = bv1[n] > TAU_F; const int i1 = bi1[n];
    float4 kf = ((const float4*)(QKV + (size_t)n * 3072 + 1024))[t];
    float4 vf = ((const float4*)(QKV + (size_t)n * 3072 + 2048))[t];
    float4 kg0 = va0 ? ((const float4*)(k0 + (size_t)i0 * 1024))[t] : kf;
    float4 vg0 = va0 ? ((const float4*)(v0 + (size_t)i0 * 1024))[t] : vf;
    float4 kg1 = va1 ? ((const float4*)(k1 + (size_t)i1 * 1024))[t] : kf;
    float4 vg1 = va1 ? ((const float4*)(v1 + (size_t)i1 * 1024))[t] : vf;
    float4 ck, cv;
    ck.x = 0.5f * kg0.x + 0.5f * kg1.x + kf.x;
    ck.y = 0.5f * kg0.y + 0.5f * kg1.y + kf.y;
    ck.z = 0.5f * kg0.z + 0.5f * kg1.z + kf.z;
    ck.w = 0.5f * kg0.w + 0.5f * kg1.w + kf.w;
    cv.x = 0.5f * vg0.x + 0.5f * vg1.x + vf.x;
    cv.y = 0.5f * vg0.y + 0.5f * vg1.y + vf.y;
    cv.z = 0.5f * vg0.z + 0.5f * vg1.z + vf.z;
    cv.w = 0.5f * vg0.w + 0.5f * vg1.w + vf.w;
    ((float4*)(CV + (size_t)n * 1024))[t] = cv;
    float s0 = vf.x * vf.x + vf.y * vf.y + vf.z * vf.z + vf.w * vf.w;
    float s1 = cv.x * cv.x + cv.y * cv.y + cv.z * cv.z + cv.w * cv.w;
    #pragma unroll
    for (int off = 32; off; off >>= 1) {
        s0 += __shfl_xor(s0, off, 64);
        s1 += __shfl_xor(s1, off, 64);
    }
    __shared__ float w0[4], w1[4];
    if ((t & 63) == 0) { w0[t >> 6] = s0; w1[t >> 6] = s1; }
    float hs = ck.x * ck.x + ck.y * ck.y + ck.z * ck.z + ck.w * ck.w;
    #pragma unroll
    for (int m = 1; m < 16; m <<= 1) hs += __shfl_xor(hs, m, 64);
    float inv = 8.0f / fmaxf(sqrtf(hs), 1e-12f);
    float4 g = ((const float4*)gamma_k)[t];
    const int h = t >> 4;
    size_t o = ((size_t)h * 4096 + n) * 64 + 4 * (t & 15);
    ushort4 hh;
    hh.x = f2bf(ck.x * inv * g.x);
    hh.y = f2bf(ck.y * inv * g.y);
    hh.z = f2bf(ck.z * inv * g.z);
    hh.w = f2bf(ck.w * inv * g.w);
    *(ushort4*)(CKh + o) = hh;
    __syncthreads();
    // per-block partial sums (plain stores) -> reduced by sumred_kernel.
    // 4096x2 contended atomicAdds to one address cost ~110us of serialization here.
    if (t == 0) {
        pps[n]        = w0[0] + w0[1] + w0[2] + w0[3];
        pps[4096 + n] = w1[0] + w1[1] + w1[2] + w1[3];
    }
}

// reduce pps[2][4096] -> ss[2]  (one block)
__global__ __launch_bounds__(256) void sumred_kernel(const float* __restrict__ pps,
                                                     float* __restrict__ ss)
{
    const int t = threadIdx.x;
    float a = 0.f, b = 0.f;
    #pragma unroll 4
    for (int i = t; i < 4096; i += 256) { a += pps[i]; b += pps[4096 + i]; }
    #pragma unroll
    for (int off = 32; off; off >>= 1) {
        a += __shfl_xor(a, off, 64);
        b += __shfl_xor(b, off, 64);
    }
    __shared__ float sa[4], sb[4];
    if ((t & 63) == 0) { sa[t >> 6] = a; sb[t >> 6] = b; }
    __syncthreads();
    if (t == 0) {
        ss[0] = sa[0] + sa[1] + sa[2] + sa[3];
        ss[1] = sb[0] + sb[1] + sb[2] + sb[3];
    }
}

// CV fp32 [4096][1024] --(*sv)--> Vt bf16 [1024][4096]
__global__ __launch_bounds__(256) void vt_kernel(const float* __restrict__ CV,
                                                 const float* __restrict__ ss,
                                                 ushort* __restrict__ Vt)
{
    __shared__ float t[64][65];
    const float sv = sqrtf(ss[0] / ss[1]);
    const int tid = threadIdx.x;
    const int n0 = blockIdx.x * 64, d0 = blockIdx.y * 64;
    #pragma unroll
    for (int i = 0; i < 16; i++) {
        int lin = i * 256 + tid;
        int r = lin >> 6, c = lin & 63;
        t[r][c] = CV[(size_t)(n0 + r) * 1024 + d0 + c];
    }
    __syncthreads();
    #pragma unroll
    for (int i = 0; i < 16; i++) {
        int lin = i * 256 + tid;
        int dr = lin >> 6, nc = lin & 63;
        Vt[(size_t)(d0 + dr) * 4096 + n0 + nc] = f2bf(t[nc][dr] * sv);
    }
}

// ===================== flash attention v6: v4 + XCD head-clustered block swizzle ==========
// grid (32 q-tiles, 16 heads), 512 threads = 8 waves, 16 q-rows each.
// KVBLK=64 -> LDS = 2x8K (K) + 2x8K (V) + 16K (Ps) = 48 KB.
// XCD swizzle: hw id round-robins XCDs; remap so each XCD owns 2 COMPLETE heads
// (K/V working set 2MB < 4MB L2) instead of touching all 16 heads (32MB thrash).
// Fixed-max softmax (|q|=|k|=8 per head): p=exp(s/8-8.5) <= 1, no online-max state.
// Swapped QK^T (mfma(K,Q) -> S^T): lane holds 4 consecutive keys for one q row;
// P -> bf16 via v_cvt_pk_bf16_f32 + one ds_write_b64 per 4 elements.
// Double-buffer: issue next tile's global_load_lds BEFORE compute; ONE barrier/iter.
__global__ __launch_bounds__(512, 6) void attn_mfma(
    const ushort* __restrict__ Qh,   // [16][4096][64]
    const ushort* __restrict__ Kh,   // [16][4096][64]
    const ushort* __restrict__ Vt,   // [16*64][4096]
    ushort* __restrict__ Hb)         // [4096][1024]
{
    __shared__ __align__(16) ushort Ks[2][64 * 64];    // 2 x 8 KB  [kv][d]
    __shared__ __align__(16) ushort Vs[2][64 * 64];    // 2 x 8 KB  [d][kv]
    __shared__ __align__(16) ushort Ps[128 * 64];      // 16 KB, wave-private rows
    const int idl = blockIdx.y * 32 + blockIdx.x;      // hw linear id (x fastest)
    const int nid = (idl & 7) * 64 + (idl >> 3);       // XCD k -> nids [64k,64k+64) = heads 2k,2k+1
    const int h = nid >> 5;
    const int n0 = (nid & 31) * 128;
    const int tid = threadIdx.x;
    const int w = tid >> 6, lane = tid & 63;
    const int quad = lane >> 4, c15 = lane & 15;

    short8 qf[2];
    #pragma unroll
    for (int kh = 0; kh < 2; kh++)
        qf[kh] = *(const short8*)(Qh + ((size_t)h * 4096 + n0 + w * 16 + c15) * 64 + kh * 32 + quad * 8);

    floatx4 po[4];
    #pragma unroll
    for (int nt = 0; nt < 4; nt++) po[nt] = (floatx4){0.f, 0.f, 0.f, 0.f};
    float lsum = 0.f;

    // p = exp(s*0.125 - 8.5) = exp2(s*(log2e/8) - 8.5*log2e)
    const float KSC = 0.18033688011112042f;     // log2(e)/8
    const float KBI = -12.262907847556189f;     // -8.5*log2(e)

    const int prow = w * 16 + c15;              // this lane's q-row in Ps (wave-private)
    const ushort* Kbase = Kh + (size_t)h * 4096 * 64;
    const ushort* Vbase = Vt + (size_t)h * 64 * 4096;

    // prologue: stage tile 0 into buffer 0 (64 kv rows x 64 d; rows are 128B = 8 chunks)
    stage_swz<8, 8, 8>(Ks[0], (const char*)(Kbase + 0), 128, w, lane);
    stage_swz<8, 8, 8>(Vs[0], (const char*)(Vbase + 0), 8192, w, lane);
    __syncthreads();

    int cur = 0;
    for (int it = 0; it < 64; ++it) {
        // issue next tile's loads into the other buffer (overlaps with compute below)
        if (it + 1 < 64) {
            const int m1 = (it + 1) * 64;
            stage_swz<8, 8, 8>(Ks[cur ^ 1], (const char*)(Kbase + (size_t)m1 * 64), 128, w, lane);
            stage_swz<8, 8, 8>(Vs[cur ^ 1], (const char*)(Vbase + m1), 8192, w, lane);
        }
        const ushort* Kc = Ks[cur];
        const ushort* Vc = Vs[cur];

        floatx4 s[4];
        #pragma unroll
        for (int nt = 0; nt < 4; nt++) {
            int rk = nt * 16 + c15;
            short8 ka = *(const short8*)&Kc[rk * 64 + swz(rk, quad, 7) * 8];
            short8 kb = *(const short8*)&Kc[rk * 64 + swz(rk, 4 + quad, 7) * 8];
            floatx4 z = (floatx4){0.f, 0.f, 0.f, 0.f};
            // swapped: A=K rows, B=Q -> z = S^T: lane holds S[k=nt*16+quad*4+r][q=c15]
            z = __builtin_amdgcn_mfma_f32_16x16x32_bf16(ka, qf[0], z, 0, 0, 0);
            z = __builtin_amdgcn_mfma_f32_16x16x32_bf16(kb, qf[1], z, 0, 0, 0);
            s[nt] = z;
        }
        // softmax partial: 4 consecutive keys per lane -> cvt_pk + single b64 write.
        // write swizzle (8B units): ch = (nt*4+quad) ^ ((row&7)<<1); its 16B view is
        // j ^ (row&7), identical to the read swizzle below.
        #pragma unroll
        for (int nt = 0; nt < 4; nt++) {
            float p0 = exp2_fast(fmaf(s[nt][0], KSC, KBI));
            float p1 = exp2_fast(fmaf(s[nt][1], KSC, KBI));
            float p2 = exp2_fast(fmaf(s[nt][2], KSC, KBI));
            float p3 = exp2_fast(fmaf(s[nt][3], KSC, KBI));
            lsum += (p0 + p1) + (p2 + p3);
            uint2 pk;
            pk.x = cvt_pk_bf16(p0, p1);
            pk.y = cvt_pk_bf16(p2, p3);
            int ch = (nt * 4 + quad) ^ ((prow & 7) << 1);
            *(uint2*)&Ps[prow * 64 + ch * 4] = pk;
        }
        __builtin_amdgcn_wave_barrier();   // order Ps writes before cross-lane reads
        #pragma unroll
        for (int kb2 = 0; kb2 < 2; kb2++) {
            short8 pa = *(const short8*)&Ps[prow * 64 + swz(prow, kb2 * 4 + quad, 7) * 8];
            #pragma unroll
            for (int nt = 0; nt < 4; nt++) {
                int dr = nt * 16 + c15;
                int j = kb2 * 4 + quad;
                short8 vb = *(const short8*)&Vc[dr * 64 + swz(dr, j, 7) * 8];
                po[nt] = __builtin_amdgcn_mfma_f32_16x16x32_bf16(pa, vb, po[nt], 0, 0, 0);
            }
        }
        // one barrier per iter: drains this wave's staged loads (vmcnt) + LDS ops,
        // so after it the OTHER buffer is fully populated for the next iteration.
        __syncthreads();
        cur ^= 1;
    }
    // lsum is per (q=c15, quad-partial); reduce across quads -> full l per q=c15
    float l = lsum;
    l += __shfl_xor(l, 16, 64);
    l += __shfl_xor(l, 32, 64);
    #pragma unroll
    for (int r = 0; r < 4; r++) {
        float lr = __shfl(l, quad * 4 + r, 64);   // l for output q-row quad*4+r
        float inv = 1.0f / lr;
        int row = n0 + w * 16 + quad * 4 + r;
        #pragma unroll
        for (int nt = 0; nt < 4; nt++)
            Hb[(size_t)row * 1024 + h * 64 + nt * 16 + c15] = f2bf(po[nt][r] * inv);
    }
}

// ===================== launcher =====================
extern "C" void kernel_launch(void* const* d_in, const int* in_sizes, int n_in,
                              void* d_out, int out_size, void* d_ws, size_t ws_size,
                              hipStream_t stream)
{
    const float* x       = (const float*)d_in[0];
    const float* k0      = (const float*)d_in[1];
    const float* v0      = (const float*)d_in[2];
    const float* k1      = (const float*)d_in[3];
    const float* v1      = (const float*)d_in[4];
    const float* W_qkv   = (const float*)d_in[5];
    const float* b_qkv   = (const float*)d_in[6];
    const float* gamma_q = (const float*)d_in[7];
    const float* gamma_k = (const float*)d_in[8];
    const float* W_out   = (const float*)d_in[9];
    const float* b_out   = (const float*)d_in[10];
    float* out = (float*)d_out;

    char* W = (char*)d_ws;
    // Region A (0..48M): QKV fp32; after combine reused for Vt + Hb
    float*  QKV = (float*)(W + 0);
    ushort* Vt  = (ushort*)(W + 0);
    ushort* Hb  = (ushort*)(W + 8388608);
    // Region B (48M..56M): Qb
    ushort* Qbh = (ushort*)(W + 50331648);
    // Region C (64M..96M): phased
    ushort* xh   = (ushort*)(W + 67108864);                 // 8 MB   (phase 1)
    ushort* Wqh  = (ushort*)(W + 67108864 + 8388608);       // 6 MB   (phase 1)
    char*   kq   = (char*)(W + 67108864);                   // 4 MB   (phase 2)
    char*   k01q = (char*)(W + 67108864 + 4194304);         // 8 MB   (phase 2)
    float*  pval = (float*)(W + 67108864 + 25165824);       // 1 MB
    int*    pidx = (int*)  (W + 67108864 + 26214400);       // 1 MB
    float*  CV   = (float*)(W + 67108864);                  // 16 MB  (phase 3)
    ushort* CKh  = (ushort*)(W + 67108864 + 16777216);      // 8 MB   (phase 3)
    ushort* Wob  = (ushort*)(W + 67108864);                 // 2 MB   (phase 4, CV dead)
    // Region D (96M..): small
    float* bv0  = (float*)(W + 100663296);
    int*   bi0  = (int*)  (W + 100663296 + 16384);
    float* bv1  = (float*)(W + 100663296 + 32768);
    int*   bi1  = (int*)  (W + 100663296 + 49152);
    float* ssum = (float*)(W + 100663296 + 65536);
    float* pps  = (float*)(W + 100663296 + 131072);         // 32 KB [2][4096]

    // 1. convert inputs for QKV GEMM (plain bf16)
    xconv_kernel<<<4096, 256, 0, stream>>>(x, xh);
    wtrans_kernel<<<dim3(48, 16), 256, 0, stream>>>(W_qkv, 1024, 3072, Wqh);
    // 2. QKV = x @ W_qkv + b (plain bf16, XCD-swizzled tiles)
    gemm_nt_kernel<<<dim3(24, 32), 256, 0, stream>>>(xh, 1024, Wqh, 1024,
                                                     b_qkv, QKV, 3072, 1024);
    // 3. prep: q mh_rms->bf16 [h][n][d] + i8-normalized rows for sim (one launch)
    prep_kernel<<<dim3(4096, 4), 256, 0, stream>>>(QKV, k0, k1, gamma_q, kq, k01q, Qbh);
    // 4. sim + top-1 over concatenated [k0;k1] (int8 MFMA, 2x rate, XCD-swizzled)
    simmax_i8<<<dim3(64, 32), 256, 0, stream>>>(kq, k01q, pval, pidx);
    simreduce2_kernel<<<16, 256, 0, stream>>>(pval, pidx, bv0, bi0, bv1, bi1);
    // 5. combine (+mh_rms k fused; sk cancels) -> CKh, CV fp32, sumsq partials
    combine_kernel<<<4096, 256, 0, stream>>>(QKV, k0, v0, k1, v1, bv0, bi0, bv1, bi1,
                                             gamma_k, CKh, CV, pps);
    // 5b. reduce partials -> ssum (replaces 8192 same-address atomics, ~110us saved)
    sumred_kernel<<<1, 256, 0, stream>>>(pps, ssum);
    // 6. V: scale by sv + transpose -> Vt bf16 [1024][4096]
    vt_kernel<<<dim3(64, 16), 256, 0, stream>>>(CV, ssum, Vt);
    // 7. W_out transpose -> bf16 (CV dead now)
    wtrans_kernel<<<dim3(16, 16), 256, 0, stream>>>(W_out, 1024, 1024, Wob);
    // 8. flash attention v6 (v4 structure + XCD head-clustered swizzle)
    attn_mfma<<<dim3(32, 16), 512, 0, stream>>>(Qbh, CKh, Vt, Hb);
    // 9. out = Hb @ W_out^T + b_out (128x64 tiles, XCD-swizzled)
    gemm_nt64_kernel<<<dim3(16, 32), 256, 0, stream>>>(Hb, 1024, Wob, 1024,
                                                       b_out, out, 1024, 1024);
}

// Round 9
// 402.422 us; speedup vs baseline: 1.0464x; 1.0299x over previous
//
#include <hip/hip_runtime.h>
#include <math.h>

#define TAU_F 0.6f

typedef short short8 __attribute__((ext_vector_type(8)));
typedef float floatx4 __attribute__((ext_vector_type(4)));
typedef int   intx4  __attribute__((ext_vector_type(4)));

__device__ __forceinline__ ushort f2bf(float f) {
    unsigned u = __float_as_uint(f);
    u += 0x7FFF + ((u >> 16) & 1);
    return (ushort)(u >> 16);
}
__device__ __forceinline__ float bf2f(ushort h) {
    return __uint_as_float(((unsigned)h) << 16);
}
__device__ __forceinline__ int swz(int row, int j, int mask) { return j ^ (row & mask); }

// packed fp32x2 -> bf16x2 (RNE), single VOP3 instruction
__device__ __forceinline__ unsigned cvt_pk_bf16(float lo, float hi) {
    unsigned r;
    asm("v_cvt_pk_bf16_f32 %0, %1, %2" : "=v"(r) : "v"(lo), "v"(hi));
    return r;
}
// raw v_exp_f32 (computes 2^x)
__device__ __forceinline__ float exp2_fast(float x) {
    float r; asm("v_exp_f32 %0, %1" : "=v"(r) : "v"(x)); return r;
}

// Stage a tile from global into LDS with XOR-chunk swizzle via global_load_lds (16B).
// SC = number of 1KB superchunks; CPR = 16B chunks per row; NW = waves in block.
template<int CPR, int SC, int NW = 4>
__device__ __forceinline__ void stage_swz(void* lds, const char* g, int rowstride_bytes,
                                          int w, int lane)
{
    #pragma unroll
    for (int p = 0; p < (SC + NW - 1) / NW; ++p) {
        int sc = w + p * NW;
        if (SC % NW != 0 && sc >= SC) break;
        int LC = sc * 64 + lane;
        int r = LC / CPR;
        int s = LC % CPR;
        int j = s ^ (r & (CPR - 1));
        const char* gp = g + (size_t)r * rowstride_bytes + j * 16;
        __builtin_amdgcn_global_load_lds(
            (const __attribute__((address_space(1))) void*)gp,
            (__attribute__((address_space(3))) void*)((char*)lds + sc * 1024), 16, 0, 0);
    }
}

// ===================== MFMA NT GEMM (bf16): C[M,N] = A[M,K] * Bt[N,K]^T + bias ==========
__global__ __launch_bounds__(256) void gemm_nt_kernel(
    const ushort* __restrict__ Ah, int lda,
    const ushort* __restrict__ Bh, int ldb,
    const float* __restrict__ bias, float* __restrict__ C, int ldc, int K)
{
    __shared__ __align__(16) ushort As_h[128 * 32];
    __shared__ __align__(16) ushort Bs_h[128 * 32];
    const int tid = threadIdx.x;
    const int w = tid >> 6, lane = tid & 63;
    const int quad = lane >> 4, c15 = lane & 15;
    const int wm = w >> 1, wn = w & 1;
    const int bm = blockIdx.y * 128, bn = blockIdx.x * 128;

    floatx4 acc[4][4];
    #pragma unroll
    for (int i = 0; i < 4; i++)
        #pragma unroll
        for (int j = 0; j < 4; j++) acc[i][j] = (floatx4){0.f, 0.f, 0.f, 0.f};

    const char* Ab = (const char*)(Ah + (size_t)bm * lda);
    const char* Bb = (const char*)(Bh + (size_t)bn * ldb);

    for (int k0 = 0; k0 < K; k0 += 32) {
        stage_swz<4, 8>(As_h, Ab + k0 * 2, lda * 2, w, lane);
        stage_swz<4, 8>(Bs_h, Bb + k0 * 2, ldb * 2, w, lane);
        __syncthreads();
        short8 a_h[4], b_h[4];
        #pragma unroll
        for (int mt = 0; mt < 4; mt++) {
            int row = wm * 64 + mt * 16 + c15;
            a_h[mt] = *(const short8*)&As_h[row * 32 + swz(row, quad, 3) * 8];
        }
        #pragma unroll
        for (int nt = 0; nt < 4; nt++) {
            int row = wn * 64 + nt * 16 + c15;
            b_h[nt] = *(const short8*)&Bs_h[row * 32 + swz(row, quad, 3) * 8];
        }
        #pragma unroll
        for (int mt = 0; mt < 4; mt++)
            #pragma unroll
            for (int nt = 0; nt < 4; nt++)
                acc[mt][nt] = __builtin_amdgcn_mfma_f32_16x16x32_bf16(a_h[mt], b_h[nt], acc[mt][nt], 0, 0, 0);
        __syncthreads();
    }
    #pragma unroll
    for (int mt = 0; mt < 4; mt++)
        #pragma unroll
        for (int nt = 0; nt < 4; nt++) {
            int col = bn + wn * 64 + nt * 16 + c15;
            float bs = bias ? bias[col] : 0.f;
            #pragma unroll
            for (int r = 0; r < 4; r++) {
                int row = bm + wm * 64 + mt * 16 + quad * 4 + r;
                C[(size_t)row * ldc + col] = acc[mt][nt][r] + bs;
            }
        }
}

// ===================== MFMA NT GEMM, 128x64 tile (for N-small GEMMs: more blocks) =========
__global__ __launch_bounds__(256) void gemm_nt64_kernel(
    const ushort* __restrict__ Ah, int lda,
    const ushort* __restrict__ Bh, int ldb,
    const float* __restrict__ bias, float* __restrict__ C, int ldc, int K)
{
    __shared__ __align__(16) ushort As_h[128 * 32];
    __shared__ __align__(16) ushort Bs_h[64 * 32];
    const int tid = threadIdx.x;
    const int w = tid >> 6, lane = tid & 63;
    const int quad = lane >> 4, c15 = lane & 15;
    const int wm = w >> 1, wn = w & 1;
    const int bm = blockIdx.y * 128, bn = blockIdx.x * 64;

    floatx4 acc[4][2];
    #pragma unroll
    for (int i = 0; i < 4; i++)
        #pragma unroll
        for (int j = 0; j < 2; j++) acc[i][j] = (floatx4){0.f, 0.f, 0.f, 0.f};

    const char* Ab = (const char*)(Ah + (size_t)bm * lda);
    const char* Bb = (const char*)(Bh + (size_t)bn * ldb);

    for (int k0 = 0; k0 < K; k0 += 32) {
        stage_swz<4, 8>(As_h, Ab + k0 * 2, lda * 2, w, lane);
        stage_swz<4, 4>(Bs_h, Bb + k0 * 2, ldb * 2, w, lane);
        __syncthreads();
        short8 a_h[4], b_h[2];
        #pragma unroll
        for (int mt = 0; mt < 4; mt++) {
            int row = wm * 64 + mt * 16 + c15;
            a_h[mt] = *(const short8*)&As_h[row * 32 + swz(row, quad, 3) * 8];
        }
        #pragma unroll
        for (int nt = 0; nt < 2; nt++) {
            int row = wn * 32 + nt * 16 + c15;
            b_h[nt] = *(const short8*)&Bs_h[row * 32 + swz(row, quad, 3) * 8];
        }
        #pragma unroll
        for (int mt = 0; mt < 4; mt++)
            #pragma unroll
            for (int nt = 0; nt < 2; nt++)
                acc[mt][nt] = __builtin_amdgcn_mfma_f32_16x16x32_bf16(a_h[mt], b_h[nt], acc[mt][nt], 0, 0, 0);
        __syncthreads();
    }
    #pragma unroll
    for (int mt = 0; mt < 4; mt++)
        #pragma unroll
        for (int nt = 0; nt < 2; nt++) {
            int col = bn + wn * 32 + nt * 16 + c15;
            float bs = bias ? bias[col] : 0.f;
            #pragma unroll
            for (int r = 0; r < 4; r++) {
                int row = bm + wm * 64 + mt * 16 + quad * 4 + r;
                C[(size_t)row * ldc + col] = acc[mt][nt][r] + bs;
            }
        }
}

// ===================== sim GEMM (int8, K=64 MFMA) with fused per-row max/argmax ==========
// A [4096][1024] i8, B [8192][1024] i8 (k0||k1), both rows pre-normalized+quantized x127.
__global__ __launch_bounds__(256) void simmax_i8(
    const char* __restrict__ A, const char* __restrict__ B,
    float* __restrict__ pval, int* __restrict__ pidx)
{
    __shared__ __align__(16) char As_b[128 * 64];
    __shared__ __align__(16) char Bs_b[128 * 64];
    __shared__ float redv[128][2];
    __shared__ int   redi[128][2];
    const int tid = threadIdx.x;
    const int w = tid >> 6, lane = tid & 63;
    const int quad = lane >> 4, c15 = lane & 15;
    const int wm = w >> 1, wn = w & 1;
    const int bm = blockIdx.y * 128, bn = blockIdx.x * 128;

    intx4 acc[4][4];
    #pragma unroll
    for (int i = 0; i < 4; i++)
        #pragma unroll
        for (int j = 0; j < 4; j++) acc[i][j] = (intx4){0, 0, 0, 0};

    const char* Ab = A + (size_t)bm * 1024;
    const char* Bb = B + (size_t)bn * 1024;

    for (int k0 = 0; k0 < 1024; k0 += 64) {
        stage_swz<4, 8>(As_b, Ab + k0, 1024, w, lane);
        stage_swz<4, 8>(Bs_b, Bb + k0, 1024, w, lane);
        __syncthreads();
        intx4 a_f[4], b_f[4];
        #pragma unroll
        for (int mt = 0; mt < 4; mt++) {
            int row = wm * 64 + mt * 16 + c15;
            a_f[mt] = *(const intx4*)&As_b[row * 64 + swz(row, quad, 3) * 16];
        }
        #pragma unroll
        for (int nt = 0; nt < 4; nt++) {
            int row = wn * 64 + nt * 16 + c15;
            b_f[nt] = *(const intx4*)&Bs_b[row * 64 + swz(row, quad, 3) * 16];
        }
        #pragma unroll
        for (int mt = 0; mt < 4; mt++)
            #pragma unroll
            for (int nt = 0; nt < 4; nt++)
                acc[mt][nt] = __builtin_amdgcn_mfma_i32_16x16x64_i8(a_f[mt], b_f[nt], acc[mt][nt], 0, 0, 0);
        __syncthreads();
    }
    const float isc = 1.0f / 16129.0f;   // 1/(127*127)
    #pragma unroll
    for (int mt = 0; mt < 4; mt++)
        #pragma unroll
        for (int r = 0; r < 4; r++) {
            float bv = -1e30f; int bi = 0;
            #pragma unroll
            for (int nt = 0; nt < 4; nt++) {
                float v = (float)acc[mt][nt][r] * isc;
                int col = bn + wn * 64 + nt * 16 + c15;
                if (v > bv) { bv = v; bi = col; }
            }
            #pragma unroll
            for (int m = 1; m < 16; m <<= 1) {
                float ov = __shfl_xor(bv, m, 64);
                int   oi = __shfl_xor(bi, m, 64);
                if (ov > bv || (ov == bv && oi < bi)) { bv = ov; bi = oi; }
            }
            if (c15 == 0) {
                int row = wm * 64 + mt * 16 + quad * 4 + r;
                redv[row][wn] = bv; redi[row][wn] = bi;
            }
        }
    __syncthreads();
    if (tid < 128) {
        float v0 = redv[tid][0], v1 = redv[tid][1];
        int   i0 = redi[tid][0], i1 = redi[tid][1];
        bool t = (v1 > v0) || (v1 == v0 && i1 < i0);
        pval[(size_t)blockIdx.x * 4096 + bm + tid] = t ? v1 : v0;
        pidx[(size_t)blockIdx.x * 4096 + bm + tid] = t ? i1 : i0;
    }
}

// fused reduce for both halves
__global__ void simreduce2_kernel(const float* __restrict__ pval, const int* __restrict__ pidx,
                                  float* __restrict__ bv0, int* __restrict__ bi0,
                                  float* __restrict__ bv1, int* __restrict__ bi1)
{
    const int n = blockIdx.x * 256 + threadIdx.x;
    float best = -1e30f; int besti = 0x7fffffff;
    for (int c = 0; c < 32; c++) {
        float v = pval[(size_t)c * 4096 + n]; int ix = pidx[(size_t)c * 4096 + n];
        if (v > best || (v == best && ix < besti)) { best = v; besti = ix; }
    }
    bv0[n] = best; bi0[n] = besti;
    best = -1e30f; besti = 0x7fffffff;
    for (int c = 32; c < 64; c++) {
        float v = pval[(size_t)c * 4096 + n]; int ix = pidx[(size_t)c * 4096 + n];
        if (v > best || (v == best && ix < besti)) { best = v; besti = ix; }
    }
    bv1[n] = best; bi1[n] = besti - 4096;
}

// ===================== conversions =====================
__global__ __launch_bounds__(256) void xconv_kernel(const float* __restrict__ s,
                                                    ushort* __restrict__ dh)
{
    const int i = blockIdx.x * 256 + threadIdx.x;
    float4 v = ((const float4*)s)[i];
    ushort4 h;
    h.x = f2bf(v.x); h.y = f2bf(v.y); h.z = f2bf(v.z); h.w = f2bf(v.w);
    ((ushort4*)dh)[i] = h;
}

__global__ __launch_bounds__(256) void wtrans_kernel(const float* __restrict__ src, int R, int Cc,
                                                     ushort* __restrict__ dh)
{
    __shared__ float t[64][65];
    const int tid = threadIdx.x;
    const int c0 = blockIdx.x * 64, r0 = blockIdx.y * 64;
    #pragma unroll
    for (int i = 0; i < 16; i++) {
        int lin = i * 256 + tid;
        int rr = lin >> 6, cc = lin & 63;
        t[rr][cc] = src[(size_t)(r0 + rr) * Cc + c0 + cc];
    }
    __syncthreads();
    #pragma unroll
    for (int i = 0; i < 16; i++) {
        int lin = i * 256 + tid;
        int cc2 = lin >> 6, rr2 = lin & 63;
        dh[(size_t)(c0 + cc2) * R + r0 + rr2] = f2bf(t[rr2][cc2]);
    }
}

__device__ __forceinline__ char q127(float v) {
    float c = fminf(fmaxf(v * 127.0f, -127.0f), 127.0f);
    return (char)__float2int_rn(c);
}

// y=0..2: l2-normalize rows -> int8 (sim path). y=3: q mh_rms -> bf16 [h][n][d].
// grid (4096, 4), 256 threads.
__global__ __launch_bounds__(256) void prep_kernel(const float* __restrict__ QKV,
                                                   const float* __restrict__ k0,
                                                   const float* __restrict__ k1,
                                                   const float* __restrict__ gamma_q,
                                                   char* __restrict__ kq,       // [4096][1024] i8
                                                   char* __restrict__ k01q,     // [8192][1024] i8
                                                   ushort* __restrict__ Qbh)    // [16][4096][64]
{
    const int n = blockIdx.x, t = threadIdx.x, y = blockIdx.y;
    if (y == 3) {
        // q: per-head rms (16 lanes per head), write bf16 [h][n][d]
        float4 v = ((const float4*)(QKV + (size_t)n * 3072))[t];
        float hs = v.x * v.x + v.y * v.y + v.z * v.z + v.w * v.w;
        #pragma unroll
        for (int m = 1; m < 16; m <<= 1) hs += __shfl_xor(hs, m, 64);
        float inv = 8.0f / fmaxf(sqrtf(hs), 1e-12f);
        float4 g = ((const float4*)gamma_q)[t];
        const int h = t >> 4;
        size_t o = ((size_t)h * 4096 + n) * 64 + 4 * (t & 15);
        ushort4 hh;
        hh.x = f2bf(v.x * inv * g.x);
        hh.y = f2bf(v.y * inv * g.y);
        hh.z = f2bf(v.z * inv * g.z);
        hh.w = f2bf(v.w * inv * g.w);
        *(ushort4*)(Qbh + o) = hh;
        return;
    }
    const float* src; int ld; char* dst;
    if (y == 0)      { src = QKV + 1024; ld = 3072; dst = kq; }
    else if (y == 1) { src = k0; ld = 1024; dst = k01q; }
    else             { src = k1; ld = 1024; dst = k01q + (size_t)4096 * 1024; }
    float4 v = *(const float4*)(src + (size_t)n * ld + 4 * t);
    float ss = v.x * v.x + v.y * v.y + v.z * v.z + v.w * v.w;
    #pragma unroll
    for (int off = 32; off; off >>= 1) ss += __shfl_xor(ss, off, 64);
    __shared__ float wsum[4];
    if ((t & 63) == 0) wsum[t >> 6] = ss;
    __syncthreads();
    float inv = 1.0f / fmaxf(sqrtf(wsum[0] + wsum[1] + wsum[2] + wsum[3]), 1e-12f);
    char4 o;
    o.x = q127(v.x * inv); o.y = q127(v.y * inv);
    o.z = q127(v.z * inv); o.w = q127(v.w * inv);
    *(char4*)(dst + (size_t)n * 1024 + 4 * t) = o;
}

// combine + per-head mh_rms(k) -> CKh [16][4096][64]; CV fp32 + per-block sumsq partials
__global__ __launch_bounds__(256) void combine_kernel(
    const float* __restrict__ QKV,
    const float* __restrict__ k0, const float* __restrict__ v0,
    const float* __restrict__ k1, const float* __restrict__ v1,
    const float* __restrict__ bv0, const int* __restrict__ bi0,
    const float* __restrict__ bv1, const int* __restrict__ bi1,
    const float* __restrict__ gamma_k,
    ushort* __restrict__ CKh,
    float* __restrict__ CV, float* __restrict__ pps)   // pps[2][4096]
{
    const int n = blockIdx.x, t = threadIdx.x;
    const bool va0 = bv0[n] > TAU_F; const int i0 = bi0[n];
    const bool va1 = bv1[n] > TAU_F; const int i1 = bi1[n];
    float4 kf = ((const float4*)(QKV + (size_t)n * 3072 + 1024))[t];
    float4 vf = ((const float4*)(QKV + (size_t)n * 3072 + 2048))[t];
    float4 kg0 = va0 ? ((const float4*)(k0 + (size_t)i0 * 1024))[t] : kf;
    float4 vg0 = va0 ? ((const float4*)(v0 + (size_t)i0 * 1024))[t] : vf;
    float4 kg1 = va1 ? ((const float4*)(k1 + (size_t)i1 * 1024))[t] : kf;
    float4 vg1 = va1 ? ((const float4*)(v1 + (size_t)i1 * 1024))[t] : vf;
    float4 ck, cv;
    ck.x = 0.5f * kg0.x + 0.5f * kg1.x + kf.x;
    ck.y = 0.5f * kg0.y + 0.5f * kg1.y + kf.y;
    ck.z = 0.5f * kg0.z + 0.5f * kg1.z + kf.z;
    ck.w = 0.5f * kg0.w + 0.5f * kg1.w + kf.w;
    cv.x = 0.5f * vg0.x + 0.5f * vg1.x + vf.x;
    cv.y = 0.5f * vg0.y + 0.5f * vg1.y + vf.y;
    cv.z = 0.5f * vg0.z + 0.5f * vg1.z + vf.z;
    cv.w = 0.5f * vg0.w + 0.5f * vg1.w + vf.w;
    ((float4*)(CV + (size_t)n * 1024))[t] = cv;
    float s0 = vf.x * vf.x + vf.y * vf.y + vf.z * vf.z + vf.w * vf.w;
    float s1 = cv.x * cv.x + cv.y * cv.y + cv.z * cv.z + cv.w * cv.w;
    #pragma unroll
    for (int off = 32; off; off >>= 1) {
        s0 += __shfl_xor(s0, off, 64);
        s1 += __shfl_xor(s1, off, 64);
    }
    __shared__ float w0[4], w1[4];
    if ((t & 63) == 0) { w0[t >> 6] = s0; w1[t >> 6] = s1; }
    float hs = ck.x * ck.x + ck.y * ck.y + ck.z * ck.z + ck.w * ck.w;
    #pragma unroll
    for (int m = 1; m < 16; m <<= 1) hs += __shfl_xor(hs, m, 64);
    float inv = 8.0f / fmaxf(sqrtf(hs), 1e-12f);
    float4 g = ((const float4*)gamma_k)[t];
    const int h = t >> 4;
    size_t o = ((size_t)h * 4096 + n) * 64 + 4 * (t & 15);
    ushort4 hh;
    hh.x = f2bf(ck.x * inv * g.x);
    hh.y = f2bf(ck.y * inv * g.y);
    hh.z = f2bf(ck.z * inv * g.z);
    hh.w = f2bf(ck.w * inv * g.w);
    *(ushort4*)(CKh + o) = hh;
    __syncthreads();
    // per-block partial sums (plain stores) -> reduced by sumred_kernel.
    // 4096x2 contended atomicAdds to one address cost ~110us of serialization here.
    if (t == 0) {
        pps[n]        = w0[0] + w0[1] + w0[2] + w0[3];
        pps[4096 + n] = w1[0] + w1[1] + w1[2] + w1[3];
    }
}

// reduce pps[2][4096] -> ss[2]  (one block)
__global__ __launch_bounds__(256) void sumred_kernel(const float* __restrict__ pps,
                                                     float* __restrict__ ss)
{
    const int t = threadIdx.x;
    float a = 0.f, b = 0.f;
    #pragma unroll 4
    for (int i = t; i < 4096; i += 256) { a += pps[i]; b += pps[4096 + i]; }
    #pragma unroll
    for (int off = 32; off; off >>= 1) {
        a += __shfl_xor(a, off, 64);
        b += __shfl_xor(b, off, 64);
    }
    __shared__ float sa[4], sb[4];
    if ((t & 63) == 0) { sa[t >> 6] = a; sb[t >> 6] = b; }
    __syncthreads();
    if (t == 0) {
        ss[0] = sa[0] + sa[1] + sa[2] + sa[3];
        ss[1] = sb[0] + sb[1] + sb[2] + sb[3];
    }
}

// CV fp32 [4096][1024] --(*sv)--> Vt bf16 [1024][4096]
__global__ __launch_bounds__(256) void vt_kernel(const float* __restrict__ CV,
                                                 const float* __restrict__ ss,
                                                 ushort* __restrict__ Vt)
{
    __shared__ float t[64][65];
    const float sv = sqrtf(ss[0] / ss[1]);
    const int tid = threadIdx.x;
    const int n0 = blockIdx.x * 64, d0 = blockIdx.y * 64;
    #pragma unroll
    for (int i = 0; i < 16; i++) {
        int lin = i * 256 + tid;
        int r = lin >> 6, c = lin & 63;
        t[r][c] = CV[(size_t)(n0 + r) * 1024 + d0 + c];
    }
    __syncthreads();
    #pragma unroll
    for (int i = 0; i < 16; i++) {
        int lin = i * 256 + tid;
        int dr = lin >> 6, nc = lin & 63;
        Vt[(size_t)(d0 + dr) * 4096 + n0 + nc] = f2bf(t[nc][dr] * sv);
    }
}

// ===================== flash attention v7: manual 2x unroll, invariant addressing ==========
// grid (32 q-tiles, 16 heads), 512 threads = 8 waves, 16 q-rows each. KVBLK=64.
// Named double buffers (Ks0/Ks1, Vs0/Vs1): all LDS addresses are loop-invariant
// VGPR + compile-time offsets (no runtime cur -> ~halves per-iter VALU addressing).
// Staging: per-lane global address precomputed once; per tile = base + tile*stride.
// XCD swizzle: each XCD owns 2 complete heads (K/V 2MB < 4MB L2): FETCH 69.7->12.3MB.
// Fixed-max softmax (|q|=|k|=8 per head): p=exp(s/8-8.5) <= 1, no online-max state.
// Swapped QK^T (mfma(K,Q) -> S^T): lane holds 4 consecutive keys for one q row;
// P -> bf16 via v_cvt_pk_bf16_f32 + one ds_write_b64 per 4 elements.
__global__ __launch_bounds__(512, 6) void attn_mfma(
    const ushort* __restrict__ Qh,   // [16][4096][64]
    const ushort* __restrict__ Kh,   // [16][4096][64]
    const ushort* __restrict__ Vt,   // [16*64][4096]
    ushort* __restrict__ Hb)         // [4096][1024]
{
    __shared__ __align__(16) ushort Ks0[64 * 64], Ks1[64 * 64];   // 2 x 8 KB [kv][d]
    __shared__ __align__(16) ushort Vs0[64 * 64], Vs1[64 * 64];   // 2 x 8 KB [d][kv]
    __shared__ __align__(16) ushort Ps[128 * 64];                 // 16 KB, wave-private rows
    const int idl = blockIdx.y * 32 + blockIdx.x;      // hw linear id (x fastest)
    const int nid = (idl & 7) * 64 + (idl >> 3);       // XCD k -> heads 2k,2k+1
    const int h = nid >> 5;
    const int n0 = (nid & 31) * 128;
    const int tid = threadIdx.x;
    const int w = tid >> 6, lane = tid & 63;
    const int quad = lane >> 4, c15 = lane & 15;

    short8 qf[2];
    #pragma unroll
    for (int kh = 0; kh < 2; kh++)
        qf[kh] = *(const short8*)(Qh + ((size_t)h * 4096 + n0 + w * 16 + c15) * 64 + kh * 32 + quad * 8);

    floatx4 po[4];
    #pragma unroll
    for (int nt = 0; nt < 4; nt++) po[nt] = (floatx4){0.f, 0.f, 0.f, 0.f};
    float lsum = 0.f;

    // p = exp(s*0.125 - 8.5) = exp2(s*(log2e/8) - 8.5*log2e)
    const float KSC = 0.18033688011112042f;     // log2(e)/8
    const float KBI = -12.262907847556189f;     // -8.5*log2(e)

    const int prow = w * 16 + c15;              // this lane's q-row in Ps (wave-private)

    // per-lane staging addresses (SC=8, NW=8, CPR=8): wave w stages superchunk w.
    // K tile stride 8192 B (64 rows x 128 B); V tile stride 128 B (col offset).
    const int LC = w * 64 + lane;
    const int sr = LC >> 3, sj = (LC & 7) ^ (sr & 7);
    const char* kg = (const char*)(Kh + (size_t)h * 4096 * 64) + (size_t)sr * 128 + sj * 16;
    const char* vg = (const char*)(Vt + (size_t)h * 64 * 4096) + (size_t)sr * 8192 + sj * 16;

#define STAGE2(KDST, VDST, T)                                                        \
    do {                                                                             \
        __builtin_amdgcn_global_load_lds(                                            \
            (const __attribute__((address_space(1))) void*)(kg + (size_t)(T) * 8192),\
            (__attribute__((address_space(3))) void*)((char*)(KDST) + w * 1024),     \
            16, 0, 0);                                                               \
        __builtin_amdgcn_global_load_lds(                                            \
            (const __attribute__((address_space(1))) void*)(vg + (size_t)(T) * 128), \
            (__attribute__((address_space(3))) void*)((char*)(VDST) + w * 1024),     \
            16, 0, 0);                                                               \
    } while (0)

#define BODY(KC, VC)                                                                 \
    do {                                                                             \
        floatx4 s_[4];                                                               \
        _Pragma("unroll")                                                            \
        for (int nt = 0; nt < 4; nt++) {                                             \
            int rk = nt * 16 + c15;                                                  \
            short8 ka = *(const short8*)&KC[rk * 64 + swz(rk, quad, 7) * 8];         \
            short8 kb = *(const short8*)&KC[rk * 64 + swz(rk, 4 + quad, 7) * 8];     \
            floatx4 z = (floatx4){0.f, 0.f, 0.f, 0.f};                               \
            z = __builtin_amdgcn_mfma_f32_16x16x32_bf16(ka, qf[0], z, 0, 0, 0);      \
            z = __builtin_amdgcn_mfma_f32_16x16x32_bf16(kb, qf[1], z, 0, 0, 0);      \
            s_[nt] = z;                                                              \
        }                                                                            \
        _Pragma("unroll")                                                            \
        for (int nt = 0; nt < 4; nt++) {                                             \
            float p0 = exp2_fast(fmaf(s_[nt][0], KSC, KBI));                         \
            float p1 = exp2_fast(fmaf(s_[nt][1], KSC, KBI));                         \
            float p2 = exp2_fast(fmaf(s_[nt][2], KSC, KBI));                         \
            float p3 = exp2_fast(fmaf(s_[nt][3], KSC, KBI));                         \
            lsum += (p0 + p1) + (p2 + p3);                                           \
            uint2 pk;                                                                \
            pk.x = cvt_pk_bf16(p0, p1);                                              \
            pk.y = cvt_pk_bf16(p2, p3);                                              \
            int ch = (nt * 4 + quad) ^ ((prow & 7) << 1);                            \
            *(uint2*)&Ps[prow * 64 + ch * 4] = pk;                                   \
        }                                                                            \
        __builtin_amdgcn_wave_barrier();                                             \
        _Pragma("unroll")                                                            \
        for (int kb2 = 0; kb2 < 2; kb2++) {                                          \
            short8 pa = *(const short8*)&Ps[prow * 64 + swz(prow, kb2 * 4 + quad, 7) * 8]; \
            _Pragma("unroll")                                                        \
            for (int nt = 0; nt < 4; nt++) {                                         \
                int dr = nt * 16 + c15;                                              \
                short8 vb = *(const short8*)&VC[dr * 64 + swz(dr, kb2 * 4 + quad, 7) * 8]; \
                po[nt] = __builtin_amdgcn_mfma_f32_16x16x32_bf16(pa, vb, po[nt], 0, 0, 0); \
            }                                                                        \
        }                                                                            \
    } while (0)

    // prologue: tile 0 -> buf0
    STAGE2(Ks0, Vs0, 0);
    __syncthreads();

    for (int it = 0; it < 64; it += 2) {
        STAGE2(Ks1, Vs1, it + 1);           // it+1 <= 63 always
        BODY(Ks0, Vs0);
        __syncthreads();
        if (it + 2 < 64) STAGE2(Ks0, Vs0, it + 2);
        BODY(Ks1, Vs1);
        __syncthreads();
    }
#undef STAGE2
#undef BODY

    // lsum is per (q=c15, quad-partial); reduce across quads -> full l per q=c15
    float l = lsum;
    l += __shfl_xor(l, 16, 64);
    l += __shfl_xor(l, 32, 64);
    #pragma unroll
    for (int r = 0; r < 4; r++) {
        float lr = __shfl(l, quad * 4 + r, 64);   // l for output q-row quad*4+r
        float inv = 1.0f / lr;
        int row = n0 + w * 16 + quad * 4 + r;
        #pragma unroll
        for (int nt = 0; nt < 4; nt++)
            Hb[(size_t)row * 1024 + h * 64 + nt * 16 + c15] = f2bf(po[nt][r] * inv);
    }
}

// ===================== launcher =====================
extern "C" void kernel_launch(void* const* d_in, const int* in_sizes, int n_in,
                              void* d_out, int out_size, void* d_ws, size_t ws_size,
                              hipStream_t stream)
{
    const float* x       = (const float*)d_in[0];
    const float* k0      = (const float*)d_in[1];
    const float* v0      = (const float*)d_in[2];
    const float* k1      = (const float*)d_in[3];
    const float* v1      = (const float*)d_in[4];
    const float* W_qkv   = (const float*)d_in[5];
    const float* b_qkv   = (const float*)d_in[6];
    const float* gamma_q = (const float*)d_in[7];
    const float* gamma_k = (const float*)d_in[8];
    const float* W_out   = (const float*)d_in[9];
    const float* b_out   = (const float*)d_in[10];
    float* out = (float*)d_out;

    char* W = (char*)d_ws;
    // Region A (0..48M): QKV fp32; after combine reused for Vt + Hb
    float*  QKV = (float*)(W + 0);
    ushort* Vt  = (ushort*)(W + 0);
    ushort* Hb  = (ushort*)(W + 8388608);
    // Region B (48M..56M): Qb
    ushort* Qbh = (ushort*)(W + 50331648);
    // Region C (64M..96M): phased
    ushort* xh   = (ushort*)(W + 67108864);                 // 8 MB   (phase 1)
    ushort* Wqh  = (ushort*)(W + 67108864 + 8388608);       // 6 MB   (phase 1)
    char*   kq   = (char*)(W + 67108864);                   // 4 MB   (phase 2)
    char*   k01q = (char*)(W + 67108864 + 4194304);         // 8 MB   (phase 2)
    float*  pval = (float*)(W + 67108864 + 25165824);       // 1 MB
    int*    pidx = (int*)  (W + 67108864 + 26214400);       // 1 MB
    float*  CV   = (float*)(W + 67108864);                  // 16 MB  (phase 3)
    ushort* CKh  = (ushort*)(W + 67108864 + 16777216);      // 8 MB   (phase 3)
    ushort* Wob  = (ushort*)(W + 67108864);                 // 2 MB   (phase 4, CV dead)
    // Region D (96M..): small
    float* bv0  = (float*)(W + 100663296);
    int*   bi0  = (int*)  (W + 100663296 + 16384);
    float* bv1  = (float*)(W + 100663296 + 32768);
    int*   bi1  = (int*)  (W + 100663296 + 49152);
    float* ssum = (float*)(W + 100663296 + 65536);
    float* pps  = (float*)(W + 100663296 + 131072);         // 32 KB [2][4096]

    // 1. convert inputs for QKV GEMM (plain bf16)
    xconv_kernel<<<4096, 256, 0, stream>>>(x, xh);
    wtrans_kernel<<<dim3(48, 16), 256, 0, stream>>>(W_qkv, 1024, 3072, Wqh);
    // 2. QKV = x @ W_qkv + b (plain bf16)
    gemm_nt_kernel<<<dim3(24, 32), 256, 0, stream>>>(xh, 1024, Wqh, 1024,
                                                     b_qkv, QKV, 3072, 1024);
    // 3. prep: q mh_rms->bf16 [h][n][d] + i8-normalized rows for sim (one launch)
    prep_kernel<<<dim3(4096, 4), 256, 0, stream>>>(QKV, k0, k1, gamma_q, kq, k01q, Qbh);
    // 4. sim + top-1 over concatenated [k0;k1] (int8 MFMA, 2x rate)
    simmax_i8<<<dim3(64, 32), 256, 0, stream>>>(kq, k01q, pval, pidx);
    simreduce2_kernel<<<16, 256, 0, stream>>>(pval, pidx, bv0, bi0, bv1, bi1);
    // 5. combine (+mh_rms k fused; sk cancels) -> CKh, CV fp32, sumsq partials
    combine_kernel<<<4096, 256, 0, stream>>>(QKV, k0, v0, k1, v1, bv0, bi0, bv1, bi1,
                                             gamma_k, CKh, CV, pps);
    // 5b. reduce partials -> ssum (replaces 8192 same-address atomics, ~110us saved)
    sumred_kernel<<<1, 256, 0, stream>>>(pps, ssum);
    // 6. V: scale by sv + transpose -> Vt bf16 [1024][4096]
    vt_kernel<<<dim3(64, 16), 256, 0, stream>>>(CV, ssum, Vt);
    // 7. W_out transpose -> bf16 (CV dead now)
    wtrans_kernel<<<dim3(16, 16), 256, 0, stream>>>(W_out, 1024, 1024, Wob);
    // 8. flash attention v7 (manual 2x unroll + invariant addressing, XCD head-clustered)
    attn_mfma<<<dim3(32, 16), 512, 0, stream>>>(Qbh, CKh, Vt, Hb);
    // 9. out = Hb @ W_out^T + b_out (128x64 tiles -> 512 blocks for occupancy)
    gemm_nt64_kernel<<<dim3(16, 32), 256, 0, stream>>>(Hb, 1024, Wob, 1024,
                                                       b_out, out, 1024, 1024);
}

// Round 10
// 384.878 us; speedup vs baseline: 1.0941x; 1.0456x over previous
//
#include <hip/hip_runtime.h>
#include <math.h>

#define TAU_F 0.6f

typedef short short8 __attribute__((ext_vector_type(8)));
typedef float floatx4 __attribute__((ext_vector_type(4)));
typedef int   intx4  __attribute__((ext_vector_type(4)));

__device__ __forceinline__ ushort f2bf(float f) {
    unsigned u = __float_as_uint(f);
    u += 0x7FFF + ((u >> 16) & 1);
    return (ushort)(u >> 16);
}
__device__ __forceinline__ float bf2f(ushort h) {
    return __uint_as_float(((unsigned)h) << 16);
}
__device__ __forceinline__ int swz(int row, int j, int mask) { return j ^ (row & mask); }

// packed fp32x2 -> bf16x2 (RNE), single VOP3 instruction
__device__ __forceinline__ unsigned cvt_pk_bf16(float lo, float hi) {
    unsigned r;
    asm("v_cvt_pk_bf16_f32 %0, %1, %2" : "=v"(r) : "v"(lo), "v"(hi));
    return r;
}
// raw v_exp_f32 (computes 2^x)
__device__ __forceinline__ float exp2_fast(float x) {
    float r; asm("v_exp_f32 %0, %1" : "=v"(r) : "v"(x)); return r;
}

// Stage a tile from global into LDS with XOR-chunk swizzle via global_load_lds (16B).
// SC = number of 1KB superchunks; CPR = 16B chunks per row; NW = waves in block.
template<int CPR, int SC, int NW = 4>
__device__ __forceinline__ void stage_swz(void* lds, const char* g, int rowstride_bytes,
                                          int w, int lane)
{
    #pragma unroll
    for (int p = 0; p < (SC + NW - 1) / NW; ++p) {
        int sc = w + p * NW;
        if (SC % NW != 0 && sc >= SC) break;
        int LC = sc * 64 + lane;
        int r = LC / CPR;
        int s = LC % CPR;
        int j = s ^ (r & (CPR - 1));
        const char* gp = g + (size_t)r * rowstride_bytes + j * 16;
        __builtin_amdgcn_global_load_lds(
            (const __attribute__((address_space(1))) void*)gp,
            (__attribute__((address_space(3))) void*)((char*)lds + sc * 1024), 16, 0, 0);
    }
}

// ===================== MFMA NT GEMM (bf16): C[M,N] = A[M,K] * Bt[N,K]^T + bias ==========
__global__ __launch_bounds__(256) void gemm_nt_kernel(
    const ushort* __restrict__ Ah, int lda,
    const ushort* __restrict__ Bh, int ldb,
    const float* __restrict__ bias, float* __restrict__ C, int ldc, int K)
{
    __shared__ __align__(16) ushort As_h[128 * 32];
    __shared__ __align__(16) ushort Bs_h[128 * 32];
    const int tid = threadIdx.x;
    const int w = tid >> 6, lane = tid & 63;
    const int quad = lane >> 4, c15 = lane & 15;
    const int wm = w >> 1, wn = w & 1;
    const int bm = blockIdx.y * 128, bn = blockIdx.x * 128;

    floatx4 acc[4][4];
    #pragma unroll
    for (int i = 0; i < 4; i++)
        #pragma unroll
        for (int j = 0; j < 4; j++) acc[i][j] = (floatx4){0.f, 0.f, 0.f, 0.f};

    const char* Ab = (const char*)(Ah + (size_t)bm * lda);
    const char* Bb = (const char*)(Bh + (size_t)bn * ldb);

    for (int k0 = 0; k0 < K; k0 += 32) {
        stage_swz<4, 8>(As_h, Ab + k0 * 2, lda * 2, w, lane);
        stage_swz<4, 8>(Bs_h, Bb + k0 * 2, ldb * 2, w, lane);
        __syncthreads();
        short8 a_h[4], b_h[4];
        #pragma unroll
        for (int mt = 0; mt < 4; mt++) {
            int row = wm * 64 + mt * 16 + c15;
            a_h[mt] = *(const short8*)&As_h[row * 32 + swz(row, quad, 3) * 8];
        }
        #pragma unroll
        for (int nt = 0; nt < 4; nt++) {
            int row = wn * 64 + nt * 16 + c15;
            b_h[nt] = *(const short8*)&Bs_h[row * 32 + swz(row, quad, 3) * 8];
        }
        #pragma unroll
        for (int mt = 0; mt < 4; mt++)
            #pragma unroll
            for (int nt = 0; nt < 4; nt++)
                acc[mt][nt] = __builtin_amdgcn_mfma_f32_16x16x32_bf16(a_h[mt], b_h[nt], acc[mt][nt], 0, 0, 0);
        __syncthreads();
    }
    #pragma unroll
    for (int mt = 0; mt < 4; mt++)
        #pragma unroll
        for (int nt = 0; nt < 4; nt++) {
            int col = bn + wn * 64 + nt * 16 + c15;
            float bs = bias ? bias[col] : 0.f;
            #pragma unroll
            for (int r = 0; r < 4; r++) {
                int row = bm + wm * 64 + mt * 16 + quad * 4 + r;
                C[(size_t)row * ldc + col] = acc[mt][nt][r] + bs;
            }
        }
}

// ===================== MFMA NT GEMM, 128x64 tile (for N-small GEMMs: more blocks) =========
__global__ __launch_bounds__(256) void gemm_nt64_kernel(
    const ushort* __restrict__ Ah, int lda,
    const ushort* __restrict__ Bh, int ldb,
    const float* __restrict__ bias, float* __restrict__ C, int ldc, int K)
{
    __shared__ __align__(16) ushort As_h[128 * 32];
    __shared__ __align__(16) ushort Bs_h[64 * 32];
    const int tid = threadIdx.x;
    const int w = tid >> 6, lane = tid & 63;
    const int quad = lane >> 4, c15 = lane & 15;
    const int wm = w >> 1, wn = w & 1;
    const int bm = blockIdx.y * 128, bn = blockIdx.x * 64;

    floatx4 acc[4][2];
    #pragma unroll
    for (int i = 0; i < 4; i++)
        #pragma unroll
        for (int j = 0; j < 2; j++) acc[i][j] = (floatx4){0.f, 0.f, 0.f, 0.f};

    const char* Ab = (const char*)(Ah + (size_t)bm * lda);
    const char* Bb = (const char*)(Bh + (size_t)bn * ldb);

    for (int k0 = 0; k0 < K; k0 += 32) {
        stage_swz<4, 8>(As_h, Ab + k0 * 2, lda * 2, w, lane);
        stage_swz<4, 4>(Bs_h, Bb + k0 * 2, ldb * 2, w, lane);
        __syncthreads();
        short8 a_h[4], b_h[2];
        #pragma unroll
        for (int mt = 0; mt < 4; mt++) {
            int row = wm * 64 + mt * 16 + c15;
            a_h[mt] = *(const short8*)&As_h[row * 32 + swz(row, quad, 3) * 8];
        }
        #pragma unroll
        for (int nt = 0; nt < 2; nt++) {
            int row = wn * 32 + nt * 16 + c15;
            b_h[nt] = *(const short8*)&Bs_h[row * 32 + swz(row, quad, 3) * 8];
        }
        #pragma unroll
        for (int mt = 0; mt < 4; mt++)
            #pragma unroll
            for (int nt = 0; nt < 2; nt++)
                acc[mt][nt] = __builtin_amdgcn_mfma_f32_16x16x32_bf16(a_h[mt], b_h[nt], acc[mt][nt], 0, 0, 0);
        __syncthreads();
    }
    #pragma unroll
    for (int mt = 0; mt < 4; mt++)
        #pragma unroll
        for (int nt = 0; nt < 2; nt++) {
            int col = bn + wn * 32 + nt * 16 + c15;
            float bs = bias ? bias[col] : 0.f;
            #pragma unroll
            for (int r = 0; r < 4; r++) {
                int row = bm + wm * 64 + mt * 16 + quad * 4 + r;
                C[(size_t)row * ldc + col] = acc[mt][nt][r] + bs;
            }
        }
}

// ===================== sim GEMM v2 (int8, K=64 MFMA), 128x256 tile, 8 waves ==========
// A [4096][1024] i8, B [8192][1024] i8 (k0||k1), rows pre-normalized+quantized x127.
// 2x4 wave grid: A-panel (8KB) shared by 4 column-waves, B-panel (16KB) by 2 row-waves
// -> 24KB staged per K-step feeds 128 MFMAs (0.1875 KB/MFMA vs 0.25 at 128x128),
// and A HBM re-reads halve (x32 column blocks instead of x64).
__global__ __launch_bounds__(512, 4) void simmax_i8(
    const char* __restrict__ A, const char* __restrict__ B,
    float* __restrict__ pval, int* __restrict__ pidx)
{
    __shared__ __align__(16) char As_b[128 * 64];    // 8 KB
    __shared__ __align__(16) char Bs_b[256 * 64];    // 16 KB
    __shared__ float redv[128][4];
    __shared__ int   redi[128][4];
    const int tid = threadIdx.x;
    const int w = tid >> 6, lane = tid & 63;
    const int quad = lane >> 4, c15 = lane & 15;
    const int wm = w >> 2, wn = w & 3;
    const int bm = blockIdx.y * 128, bn = blockIdx.x * 256;

    intx4 acc[4][4];
    #pragma unroll
    for (int i = 0; i < 4; i++)
        #pragma unroll
        for (int j = 0; j < 4; j++) acc[i][j] = (intx4){0, 0, 0, 0};

    const char* Ab = A + (size_t)bm * 1024;
    const char* Bb = B + (size_t)bn * 1024;

    for (int k0 = 0; k0 < 1024; k0 += 64) {
        stage_swz<4, 8, 8>(As_b, Ab + k0, 1024, w, lane);
        stage_swz<4, 16, 8>(Bs_b, Bb + k0, 1024, w, lane);
        __syncthreads();
        intx4 a_f[4], b_f[4];
        #pragma unroll
        for (int mt = 0; mt < 4; mt++) {
            int row = wm * 64 + mt * 16 + c15;
            a_f[mt] = *(const intx4*)&As_b[row * 64 + swz(row, quad, 3) * 16];
        }
        #pragma unroll
        for (int nt = 0; nt < 4; nt++) {
            int row = wn * 64 + nt * 16 + c15;
            b_f[nt] = *(const intx4*)&Bs_b[row * 64 + swz(row, quad, 3) * 16];
        }
        #pragma unroll
        for (int mt = 0; mt < 4; mt++)
            #pragma unroll
            for (int nt = 0; nt < 4; nt++)
                acc[mt][nt] = __builtin_amdgcn_mfma_i32_16x16x64_i8(a_f[mt], b_f[nt], acc[mt][nt], 0, 0, 0);
        __syncthreads();
    }
    const float isc = 1.0f / 16129.0f;   // 1/(127*127)
    #pragma unroll
    for (int mt = 0; mt < 4; mt++)
        #pragma unroll
        for (int r = 0; r < 4; r++) {
            float bv = -1e30f; int bi = 0;
            #pragma unroll
            for (int nt = 0; nt < 4; nt++) {
                float v = (float)acc[mt][nt][r] * isc;
                int col = bn + wn * 64 + nt * 16 + c15;
                if (v > bv) { bv = v; bi = col; }
            }
            #pragma unroll
            for (int m = 1; m < 16; m <<= 1) {
                float ov = __shfl_xor(bv, m, 64);
                int   oi = __shfl_xor(bi, m, 64);
                if (ov > bv || (ov == bv && oi < bi)) { bv = ov; bi = oi; }
            }
            if (c15 == 0) {
                int row = wm * 64 + mt * 16 + quad * 4 + r;
                redv[row][wn] = bv; redi[row][wn] = bi;
            }
        }
    __syncthreads();
    if (tid < 128) {
        float bv = redv[tid][0]; int bi = redi[tid][0];
        #pragma unroll
        for (int j = 1; j < 4; j++) {
            float vj = redv[tid][j]; int ij = redi[tid][j];
            if (vj > bv || (vj == bv && ij < bi)) { bv = vj; bi = ij; }
        }
        pval[(size_t)blockIdx.x * 4096 + bm + tid] = bv;
        pidx[(size_t)blockIdx.x * 4096 + bm + tid] = bi;
    }
}

// fused reduce for both halves (32 column-chunks of 256: 0-15 = k0, 16-31 = k1)
__global__ void simreduce2_kernel(const float* __restrict__ pval, const int* __restrict__ pidx,
                                  float* __restrict__ bv0, int* __restrict__ bi0,
                                  float* __restrict__ bv1, int* __restrict__ bi1)
{
    const int n = blockIdx.x * 256 + threadIdx.x;
    float best = -1e30f; int besti = 0x7fffffff;
    for (int c = 0; c < 16; c++) {
        float v = pval[(size_t)c * 4096 + n]; int ix = pidx[(size_t)c * 4096 + n];
        if (v > best || (v == best && ix < besti)) { best = v; besti = ix; }
    }
    bv0[n] = best; bi0[n] = besti;
    best = -1e30f; besti = 0x7fffffff;
    for (int c = 16; c < 32; c++) {
        float v = pval[(size_t)c * 4096 + n]; int ix = pidx[(size_t)c * 4096 + n];
        if (v > best || (v == best && ix < besti)) { best = v; besti = ix; }
    }
    bv1[n] = best; bi1[n] = besti - 4096;
}

// ===================== conversions =====================
__global__ __launch_bounds__(256) void xconv_kernel(const float* __restrict__ s,
                                                    ushort* __restrict__ dh)
{
    const int i = blockIdx.x * 256 + threadIdx.x;
    float4 v = ((const float4*)s)[i];
    ushort4 h;
    h.x = f2bf(v.x); h.y = f2bf(v.y); h.z = f2bf(v.z); h.w = f2bf(v.w);
    ((ushort4*)dh)[i] = h;
}

__global__ __launch_bounds__(256) void wtrans_kernel(const float* __restrict__ src, int R, int Cc,
                                                     ushort* __restrict__ dh)
{
    __shared__ float t[64][65];
    const int tid = threadIdx.x;
    const int c0 = blockIdx.x * 64, r0 = blockIdx.y * 64;
    #pragma unroll
    for (int i = 0; i < 16; i++) {
        int lin = i * 256 + tid;
        int rr = lin >> 6, cc = lin & 63;
        t[rr][cc] = src[(size_t)(r0 + rr) * Cc + c0 + cc];
    }
    __syncthreads();
    #pragma unroll
    for (int i = 0; i < 16; i++) {
        int lin = i * 256 + tid;
        int cc2 = lin >> 6, rr2 = lin & 63;
        dh[(size_t)(c0 + cc2) * R + r0 + rr2] = f2bf(t[rr2][cc2]);
    }
}

__device__ __forceinline__ char q127(float v) {
    float c = fminf(fmaxf(v * 127.0f, -127.0f), 127.0f);
    return (char)__float2int_rn(c);
}

// y=0..2: l2-normalize rows -> int8 (sim path). y=3: q mh_rms -> bf16 [h][n][d].
// grid (4096, 4), 256 threads.
__global__ __launch_bounds__(256) void prep_kernel(const float* __restrict__ QKV,
                                                   const float* __restrict__ k0,
                                                   const float* __restrict__ k1,
                                                   const float* __restrict__ gamma_q,
                                                   char* __restrict__ kq,       // [4096][1024] i8
                                                   char* __restrict__ k01q,     // [8192][1024] i8
                                                   ushort* __restrict__ Qbh)    // [16][4096][64]
{
    const int n = blockIdx.x, t = threadIdx.x, y = blockIdx.y;
    if (y == 3) {
        // q: per-head rms (16 lanes per head), write bf16 [h][n][d]
        float4 v = ((const float4*)(QKV + (size_t)n * 3072))[t];
        float hs = v.x * v.x + v.y * v.y + v.z * v.z + v.w * v.w;
        #pragma unroll
        for (int m = 1; m < 16; m <<= 1) hs += __shfl_xor(hs, m, 64);
        float inv = 8.0f / fmaxf(sqrtf(hs), 1e-12f);
        float4 g = ((const float4*)gamma_q)[t];
        const int h = t >> 4;
        size_t o = ((size_t)h * 4096 + n) * 64 + 4 * (t & 15);
        ushort4 hh;
        hh.x = f2bf(v.x * inv * g.x);
        hh.y = f2bf(v.y * inv * g.y);
        hh.z = f2bf(v.z * inv * g.z);
        hh.w = f2bf(v.w * inv * g.w);
        *(ushort4*)(Qbh + o) = hh;
        return;
    }
    const float* src; int ld; char* dst;
    if (y == 0)      { src = QKV + 1024; ld = 3072; dst = kq; }
    else if (y == 1) { src = k0; ld = 1024; dst = k01q; }
    else             { src = k1; ld = 1024; dst = k01q + (size_t)4096 * 1024; }
    float4 v = *(const float4*)(src + (size_t)n * ld + 4 * t);
    float ss = v.x * v.x + v.y * v.y + v.z * v.z + v.w * v.w;
    #pragma unroll
    for (int off = 32; off; off >>= 1) ss += __shfl_xor(ss, off, 64);
    __shared__ float wsum[4];
    if ((t & 63) == 0) wsum[t >> 6] = ss;
    __syncthreads();
    float inv = 1.0f / fmaxf(sqrtf(wsum[0] + wsum[1] + wsum[2] + wsum[3]), 1e-12f);
    char4 o;
    o.x = q127(v.x * inv); o.y = q127(v.y * inv);
    o.z = q127(v.z * inv); o.w = q127(v.w * inv);
    *(char4*)(dst + (size_t)n * 1024 + 4 * t) = o;
}

// combine + per-head mh_rms(k) -> CKh [16][4096][64]; CV fp32 + per-block sumsq partials
__global__ __launch_bounds__(256) void combine_kernel(
    const float* __restrict__ QKV,
    const float* __restrict__ k0, const float* __restrict__ v0,
    const float* __restrict__ k1, const float* __restrict__ v1,
    const float* __restrict__ bv0, const int* __restrict__ bi0,
    const float* __restrict__ bv1, const int* __restrict__ bi1,
    const float* __restrict__ gamma_k,
    ushort* __restrict__ CKh,
    float* __restrict__ CV, float* __restrict__ pps)   // pps[2][4096]
{
    const int n = blockIdx.x, t = threadIdx.x;
    const bool va0 = bv0[n] > TAU_F; const int i0 = bi0[n];
    const bool va1 = bv1[n] > TAU_F; const int i1 = bi1[n];
    float4 kf = ((const float4*)(QKV + (size_t)n * 3072 + 1024))[t];
    float4 vf = ((const float4*)(QKV + (size_t)n * 3072 + 2048))[t];
    float4 kg0 = va0 ? ((const float4*)(k0 + (size_t)i0 * 1024))[t] : kf;
    float4 vg0 = va0 ? ((const float4*)(v0 + (size_t)i0 * 1024))[t] : vf;
    float4 kg1 = va1 ? ((const float4*)(k1 + (size_t)i1 * 1024))[t] : kf;
    float4 vg1 = va1 ? ((const float4*)(v1 + (size_t)i1 * 1024))[t] : vf;
    float4 ck, cv;
    ck.x = 0.5f * kg0.x + 0.5f * kg1.x + kf.x;
    ck.y = 0.5f * kg0.y + 0.5f * kg1.y + kf.y;
    ck.z = 0.5f * kg0.z + 0.5f * kg1.z + kf.z;
    ck.w = 0.5f * kg0.w + 0.5f * kg1.w + kf.w;
    cv.x = 0.5f * vg0.x + 0.5f * vg1.x + vf.x;
    cv.y = 0.5f * vg0.y + 0.5f * vg1.y + vf.y;
    cv.z = 0.5f * vg0.z + 0.5f * vg1.z + vf.z;
    cv.w = 0.5f * vg0.w + 0.5f * vg1.w + vf.w;
    ((float4*)(CV + (size_t)n * 1024))[t] = cv;
    float s0 = vf.x * vf.x + vf.y * vf.y + vf.z * vf.z + vf.w * vf.w;
    float s1 = cv.x * cv.x + cv.y * cv.y + cv.z * cv.z + cv.w * cv.w;
    #pragma unroll
    for (int off = 32; off; off >>= 1) {
        s0 += __shfl_xor(s0, off, 64);
        s1 += __shfl_xor(s1, off, 64);
    }
    __shared__ float w0[4], w1[4];
    if ((t & 63) == 0) { w0[t >> 6] = s0; w1[t >> 6] = s1; }
    float hs = ck.x * ck.x + ck.y * ck.y + ck.z * ck.z + ck.w * ck.w;
    #pragma unroll
    for (int m = 1; m < 16; m <<= 1) hs += __shfl_xor(hs, m, 64);
    float inv = 8.0f / fmaxf(sqrtf(hs), 1e-12f);
    float4 g = ((const float4*)gamma_k)[t];
    const int h = t >> 4;
    size_t o = ((size_t)h * 4096 + n) * 64 + 4 * (t & 15);
    ushort4 hh;
    hh.x = f2bf(ck.x * inv * g.x);
    hh.y = f2bf(ck.y * inv * g.y);
    hh.z = f2bf(ck.z * inv * g.z);
    hh.w = f2bf(ck.w * inv * g.w);
    *(ushort4*)(CKh + o) = hh;
    __syncthreads();
    // per-block partial sums (plain stores) -> reduced by sumred_kernel.
    if (t == 0) {
        pps[n]        = w0[0] + w0[1] + w0[2] + w0[3];
        pps[4096 + n] = w1[0] + w1[1] + w1[2] + w1[3];
    }
}

// reduce pps[2][4096] -> ss[2]  (one block)
__global__ __launch_bounds__(256) void sumred_kernel(const float* __restrict__ pps,
                                                     float* __restrict__ ss)
{
    const int t = threadIdx.x;
    float a = 0.f, b = 0.f;
    #pragma unroll 4
    for (int i = t; i < 4096; i += 256) { a += pps[i]; b += pps[4096 + i]; }
    #pragma unroll
    for (int off = 32; off; off >>= 1) {
        a += __shfl_xor(a, off, 64);
        b += __shfl_xor(b, off, 64);
    }
    __shared__ float sa[4], sb[4];
    if ((t & 63) == 0) { sa[t >> 6] = a; sb[t >> 6] = b; }
    __syncthreads();
    if (t == 0) {
        ss[0] = sa[0] + sa[1] + sa[2] + sa[3];
        ss[1] = sb[0] + sb[1] + sb[2] + sb[3];
    }
}

// CV fp32 [4096][1024] --(*sv)--> Vt bf16 [1024][4096]
__global__ __launch_bounds__(256) void vt_kernel(const float* __restrict__ CV,
                                                 const float* __restrict__ ss,
                                                 ushort* __restrict__ Vt)
{
    __shared__ float t[64][65];
    const float sv = sqrtf(ss[0] / ss[1]);
    const int tid = threadIdx.x;
    const int n0 = blockIdx.x * 64, d0 = blockIdx.y * 64;
    #pragma unroll
    for (int i = 0; i < 16; i++) {
        int lin = i * 256 + tid;
        int r = lin >> 6, c = lin & 63;
        t[r][c] = CV[(size_t)(n0 + r) * 1024 + d0 + c];
    }
    __syncthreads();
    #pragma unroll
    for (int i = 0; i < 16; i++) {
        int lin = i * 256 + tid;
        int dr = lin >> 6, nc = lin & 63;
        Vt[(size_t)(d0 + dr) * 4096 + n0 + nc] = f2bf(t[nc][dr] * sv);
    }
}

// ===================== flash attention v8: v7 + setprio around MFMA clusters ==========
// grid (32 q-tiles, 16 heads), 512 threads = 8 waves, 16 q-rows each. KVBLK=64.
// At the LDS-pipe floor (~240 LDS-cyc/wave-iter ~= measured 96us); setprio (T5) is a
// free scheduler hint that pays when co-resident blocks are at different phases.
__global__ __launch_bounds__(512, 6) void attn_mfma(
    const ushort* __restrict__ Qh,   // [16][4096][64]
    const ushort* __restrict__ Kh,   // [16][4096][64]
    const ushort* __restrict__ Vt,   // [16*64][4096]
    ushort* __restrict__ Hb)         // [4096][1024]
{
    __shared__ __align__(16) ushort Ks0[64 * 64], Ks1[64 * 64];   // 2 x 8 KB [kv][d]
    __shared__ __align__(16) ushort Vs0[64 * 64], Vs1[64 * 64];   // 2 x 8 KB [d][kv]
    __shared__ __align__(16) ushort Ps[128 * 64];                 // 16 KB, wave-private rows
    const int idl = blockIdx.y * 32 + blockIdx.x;      // hw linear id (x fastest)
    const int nid = (idl & 7) * 64 + (idl >> 3);       // XCD k -> heads 2k,2k+1
    const int h = nid >> 5;
    const int n0 = (nid & 31) * 128;
    const int tid = threadIdx.x;
    const int w = tid >> 6, lane = tid & 63;
    const int quad = lane >> 4, c15 = lane & 15;

    short8 qf[2];
    #pragma unroll
    for (int kh = 0; kh < 2; kh++)
        qf[kh] = *(const short8*)(Qh + ((size_t)h * 4096 + n0 + w * 16 + c15) * 64 + kh * 32 + quad * 8);

    floatx4 po[4];
    #pragma unroll
    for (int nt = 0; nt < 4; nt++) po[nt] = (floatx4){0.f, 0.f, 0.f, 0.f};
    float lsum = 0.f;

    // p = exp(s*0.125 - 8.5) = exp2(s*(log2e/8) - 8.5*log2e)
    const float KSC = 0.18033688011112042f;     // log2(e)/8
    const float KBI = -12.262907847556189f;     // -8.5*log2(e)

    const int prow = w * 16 + c15;              // this lane's q-row in Ps (wave-private)

    // per-lane staging addresses (SC=8, NW=8, CPR=8): wave w stages superchunk w.
    const int LC = w * 64 + lane;
    const int sr = LC >> 3, sj = (LC & 7) ^ (sr & 7);
    const char* kg = (const char*)(Kh + (size_t)h * 4096 * 64) + (size_t)sr * 128 + sj * 16;
    const char* vg = (const char*)(Vt + (size_t)h * 64 * 4096) + (size_t)sr * 8192 + sj * 16;

#define STAGE2(KDST, VDST, T)                                                        \
    do {                                                                             \
        __builtin_amdgcn_global_load_lds(                                            \
            (const __attribute__((address_space(1))) void*)(kg + (size_t)(T) * 8192),\
            (__attribute__((address_space(3))) void*)((char*)(KDST) + w * 1024),     \
            16, 0, 0);                                                               \
        __builtin_amdgcn_global_load_lds(                                            \
            (const __attribute__((address_space(1))) void*)(vg + (size_t)(T) * 128), \
            (__attribute__((address_space(3))) void*)((char*)(VDST) + w * 1024),     \
            16, 0, 0);                                                               \
    } while (0)

#define BODY(KC, VC)                                                                 \
    do {                                                                             \
        floatx4 s_[4];                                                               \
        __builtin_amdgcn_s_setprio(1);                                               \
        _Pragma("unroll")                                                            \
        for (int nt = 0; nt < 4; nt++) {                                             \
            int rk = nt * 16 + c15;                                                  \
            short8 ka = *(const short8*)&KC[rk * 64 + swz(rk, quad, 7) * 8];         \
            short8 kb = *(const short8*)&KC[rk * 64 + swz(rk, 4 + quad, 7) * 8];     \
            floatx4 z = (floatx4){0.f, 0.f, 0.f, 0.f};                               \
            z = __builtin_amdgcn_mfma_f32_16x16x32_bf16(ka, qf[0], z, 0, 0, 0);      \
            z = __builtin_amdgcn_mfma_f32_16x16x32_bf16(kb, qf[1], z, 0, 0, 0);      \
            s_[nt] = z;                                                              \
        }                                                                            \
        __builtin_amdgcn_s_setprio(0);                                               \
        _Pragma("unroll")                                                            \
        for (int nt = 0; nt < 4; nt++) {                                             \
            float p0 = exp2_fast(fmaf(s_[nt][0], KSC, KBI));                         \
            float p1 = exp2_fast(fmaf(s_[nt][1], KSC, KBI));                         \
            float p2 = exp2_fast(fmaf(s_[nt][2], KSC, KBI));                         \
            float p3 = exp2_fast(fmaf(s_[nt][3], KSC, KBI));                         \
            lsum += (p0 + p1) + (p2 + p3);                                           \
            uint2 pk;                                                                \
            pk.x = cvt_pk_bf16(p0, p1);                                              \
            pk.y = cvt_pk_bf16(p2, p3);                                              \
            int ch = (nt * 4 + quad) ^ ((prow & 7) << 1);                            \
            *(uint2*)&Ps[prow * 64 + ch * 4] = pk;                                   \
        }                                                                            \
        __builtin_amdgcn_wave_barrier();                                             \
        __builtin_amdgcn_s_setprio(1);                                               \
        _Pragma("unroll")                                                            \
        for (int kb2 = 0; kb2 < 2; kb2++) {                                          \
            short8 pa = *(const short8*)&Ps[prow * 64 + swz(prow, kb2 * 4 + quad, 7) * 8]; \
            _Pragma("unroll")                                                        \
            for (int nt = 0; nt < 4; nt++) {                                         \
                int dr = nt * 16 + c15;                                              \
                short8 vb = *(const short8*)&VC[dr * 64 + swz(dr, kb2 * 4 + quad, 7) * 8]; \
                po[nt] = __builtin_amdgcn_mfma_f32_16x16x32_bf16(pa, vb, po[nt], 0, 0, 0); \
            }                                                                        \
        }                                                                            \
        __builtin_amdgcn_s_setprio(0);                                               \
    } while (0)

    // prologue: tile 0 -> buf0
    STAGE2(Ks0, Vs0, 0);
    __syncthreads();

    for (int it = 0; it < 64; it += 2) {
        STAGE2(Ks1, Vs1, it + 1);           // it+1 <= 63 always
        BODY(Ks0, Vs0);
        __syncthreads();
        if (it + 2 < 64) STAGE2(Ks0, Vs0, it + 2);
        BODY(Ks1, Vs1);
        __syncthreads();
    }
#undef STAGE2
#undef BODY

    // lsum is per (q=c15, quad-partial); reduce across quads -> full l per q=c15
    float l = lsum;
    l += __shfl_xor(l, 16, 64);
    l += __shfl_xor(l, 32, 64);
    #pragma unroll
    for (int r = 0; r < 4; r++) {
        float lr = __shfl(l, quad * 4 + r, 64);   // l for output q-row quad*4+r
        float inv = 1.0f / lr;
        int row = n0 + w * 16 + quad * 4 + r;
        #pragma unroll
        for (int nt = 0; nt < 4; nt++)
            Hb[(size_t)row * 1024 + h * 64 + nt * 16 + c15] = f2bf(po[nt][r] * inv);
    }
}

// ===================== launcher =====================
extern "C" void kernel_launch(void* const* d_in, const int* in_sizes, int n_in,
                              void* d_out, int out_size, void* d_ws, size_t ws_size,
                              hipStream_t stream)
{
    const float* x       = (const float*)d_in[0];
    const float* k0      = (const float*)d_in[1];
    const float* v0      = (const float*)d_in[2];
    const float* k1      = (const float*)d_in[3];
    const float* v1      = (const float*)d_in[4];
    const float* W_qkv   = (const float*)d_in[5];
    const float* b_qkv   = (const float*)d_in[6];
    const float* gamma_q = (const float*)d_in[7];
    const float* gamma_k = (const float*)d_in[8];
    const float* W_out   = (const float*)d_in[9];
    const float* b_out   = (const float*)d_in[10];
    float* out = (float*)d_out;

    char* W = (char*)d_ws;
    // Region A (0..48M): QKV fp32; after combine reused for Vt + Hb
    float*  QKV = (float*)(W + 0);
    ushort* Vt  = (ushort*)(W + 0);
    ushort* Hb  = (ushort*)(W + 8388608);
    // Region B (48M..56M): Qb
    ushort* Qbh = (ushort*)(W + 50331648);
    // Region C (64M..96M): phased
    ushort* xh   = (ushort*)(W + 67108864);                 // 8 MB   (phase 1)
    ushort* Wqh  = (ushort*)(W + 67108864 + 8388608);       // 6 MB   (phase 1)
    char*   kq   = (char*)(W + 67108864);                   // 4 MB   (phase 2)
    char*   k01q = (char*)(W + 67108864 + 4194304);         // 8 MB   (phase 2)
    float*  pval = (float*)(W + 67108864 + 25165824);       // 512 KB (32x4096)
    int*    pidx = (int*)  (W + 67108864 + 26214400);       // 512 KB
    float*  CV   = (float*)(W + 67108864);                  // 16 MB  (phase 3)
    ushort* CKh  = (ushort*)(W + 67108864 + 16777216);      // 8 MB   (phase 3)
    ushort* Wob  = (ushort*)(W + 67108864);                 // 2 MB   (phase 4, CV dead)
    // Region D (96M..): small
    float* bv0  = (float*)(W + 100663296);
    int*   bi0  = (int*)  (W + 100663296 + 16384);
    float* bv1  = (float*)(W + 100663296 + 32768);
    int*   bi1  = (int*)  (W + 100663296 + 49152);
    float* ssum = (float*)(W + 100663296 + 65536);
    float* pps  = (float*)(W + 100663296 + 131072);         // 32 KB [2][4096]

    // 1. convert inputs for QKV GEMM (plain bf16)
    xconv_kernel<<<4096, 256, 0, stream>>>(x, xh);
    wtrans_kernel<<<dim3(48, 16), 256, 0, stream>>>(W_qkv, 1024, 3072, Wqh);
    // 2. QKV = x @ W_qkv + b (plain bf16)
    gemm_nt_kernel<<<dim3(24, 32), 256, 0, stream>>>(xh, 1024, Wqh, 1024,
                                                     b_qkv, QKV, 3072, 1024);
    // 3. prep: q mh_rms->bf16 [h][n][d] + i8-normalized rows for sim (one launch)
    prep_kernel<<<dim3(4096, 4), 256, 0, stream>>>(QKV, k0, k1, gamma_q, kq, k01q, Qbh);
    // 4. sim + top-1 over concatenated [k0;k1] (int8 MFMA, 128x256 tile, 8 waves)
    simmax_i8<<<dim3(32, 32), 512, 0, stream>>>(kq, k01q, pval, pidx);
    simreduce2_kernel<<<16, 256, 0, stream>>>(pval, pidx, bv0, bi0, bv1, bi1);
    // 5. combine (+mh_rms k fused; sk cancels) -> CKh, CV fp32, sumsq partials
    combine_kernel<<<4096, 256, 0, stream>>>(QKV, k0, v0, k1, v1, bv0, bi0, bv1, bi1,
                                             gamma_k, CKh, CV, pps);
    // 5b. reduce partials -> ssum
    sumred_kernel<<<1, 256, 0, stream>>>(pps, ssum);
    // 6. V: scale by sv + transpose -> Vt bf16 [1024][4096]
    vt_kernel<<<dim3(64, 16), 256, 0, stream>>>(CV, ssum, Vt);
    // 7. W_out transpose -> bf16 (CV dead now)
    wtrans_kernel<<<dim3(16, 16), 256, 0, stream>>>(W_out, 1024, 1024, Wob);
    // 8. flash attention v8 (v7 + setprio; XCD head-clustered)
    attn_mfma<<<dim3(32, 16), 512, 0, stream>>>(Qbh, CKh, Vt, Hb);
    // 9. out = Hb @ W_out^T + b_out (128x64 tiles -> 512 blocks for occupancy)
    gemm_nt64_kernel<<<dim3(16, 32), 256, 0, stream>>>(Hb, 1024, Wob, 1024,
                                                       b_out, out, 1024, 1024);
}